// Round 7
// baseline (446.522 us; speedup 1.0000x reference)
//
#include <hip/hip_runtime.h>
#include <hip/hip_bf16.h>

typedef __bf16 bf16x8 __attribute__((ext_vector_type(8)));
typedef float  f32x4  __attribute__((ext_vector_type(4)));

#define B_ROWS 65536
#define KC1 22           // 704/32
#define KC2 8            // 256/32
#define KC3 4            // 128/32
#define H1S 264          // h1 LDS stride (256+8 pad: 528B rows -> 2-way banks max)
#define H2S 136          // h2 LDS stride (128+8 pad)
#define PANEL_B 16384    // one GEMM1 B panel: 256 n x 32 ki x 2B (swizzled layout)
#define W1B_ELEMS (704*256)
#define W2B_ELEMS (256*128)
#define W3B_ELEMS (128*16)
#define W1B_BYTES (KC1*PANEL_B)                         // 360448
#define WS_WEIGHTS (W1B_BYTES + W2B_ELEMS*2 + W3B_ELEMS*2)  // 430080
#define H0B_BYTES ((size_t)B_ROWS*704*2)                // 92.3MB
#define GM 64            // rows per gemm block (split path)

// fused-fallback geometry (R3)
#define MR 32
#define H0S 712

// ---------------------------------------------------------------------------
// Pack weights to bf16 MFMA-B layouts.
// w1b: per-kc 16KB panel; element (n,ki) at byte (n*64 + ki*2) ^ ((n&7)<<4).
//   The XOR spreads the 16 l15-lanes of a ds_read_b128 across 8 bank-quads
//   (2-way max) when the panel sits in LDS. Bijective within each n-row's 64B.
// w2b/w3b: [kc][n][ki32] linear as before.
__global__ void pack_weights(const float* __restrict__ w1,
                             const float* __restrict__ w2,
                             const float* __restrict__ w3,
                             __hip_bfloat16* __restrict__ w1b,
                             __hip_bfloat16* __restrict__ w2b,
                             __hip_bfloat16* __restrict__ w3b) {
    int idx = blockIdx.x * 256 + threadIdx.x;
    if (idx < W1B_ELEMS) {
        int ki = idx & 31, t = idx >> 5;
        int n = t & 255, kc = t >> 8;
        int k = kc * 32 + ki;
        float v = (k < 676) ? w1[k * 256 + n] : 0.0f;   // zero-pad K 676->704
        size_t byte = (size_t)kc * PANEL_B + (size_t)((n * 64 + ki * 2) ^ ((n & 7) << 4));
        *(__hip_bfloat16*)((char*)w1b + byte) = __float2bfloat16(v);
    } else if (idx < W1B_ELEMS + W2B_ELEMS) {
        int j = idx - W1B_ELEMS;
        int ki = j & 31, t = j >> 5;
        int n = t & 127, kc = t >> 7;
        w2b[j] = __float2bfloat16(w2[(kc * 32 + ki) * 128 + n]);
    } else if (idx < W1B_ELEMS + W2B_ELEMS + W3B_ELEMS) {
        int j = idx - W1B_ELEMS - W2B_ELEMS;
        int ki = j & 31, t = j >> 5;
        int n = t & 15, kc = t >> 4;
        float v = (n < 10) ? w3[(kc * 32 + ki) * 10 + n] : 0.0f;  // zero-pad N 10->16
        w3b[j] = __float2bfloat16(v);
    }
}

// ---------------------------------------------------------------------------
// Split path, kernel A: conv3x3 valid, fp32 exact, h0b[r][704] bf16 to global.
// Task = (image r, out-row i, half): 3x15 window, 13 outputs. 12 float4 loads
// pinned in flight; VGPR ~80 -> 16 waves/CU (TLP) x 12 loads (MLP).
template<int S>
__device__ __forceinline__ void conv_body(
        const float* __restrict__ xr, __hip_bfloat16* __restrict__ hp,
        float c00, float c01, float c02, float c10, float c11, float c12,
        float c20, float c21, float c22) {
    float4 v[3][4];
    #pragma unroll
    for (int d = 0; d < 3; d++) {
        const float4* p4 = (const float4*)(xr + d * 28);   // rows 112B -> 16B aligned
        #pragma unroll
        for (int q = 0; q < 4; q++) v[d][q] = p4[S * 3 + q];
    }
    #pragma unroll
    for (int d = 0; d < 3; d++)
        #pragma unroll
        for (int q = 0; q < 4; q++)
            asm volatile("" :: "v"(v[d][q].x), "v"(v[d][q].y), "v"(v[d][q].z), "v"(v[d][q].w));
    float rb[3][16];
    #pragma unroll
    for (int d = 0; d < 3; d++)
        #pragma unroll
        for (int q = 0; q < 4; q++) {
            rb[d][q*4+0] = v[d][q].x; rb[d][q*4+1] = v[d][q].y;
            rb[d][q*4+2] = v[d][q].z; rb[d][q*4+3] = v[d][q].w;
        }
    #pragma unroll
    for (int jj = 0; jj < 13; jj++) {
        float a = c00*rb[0][S+jj] + c01*rb[0][S+jj+1] + c02*rb[0][S+jj+2]
                + c10*rb[1][S+jj] + c11*rb[1][S+jj+1] + c12*rb[1][S+jj+2]
                + c20*rb[2][S+jj] + c21*rb[2][S+jj+1] + c22*rb[2][S+jj+2];
        hp[jj] = __float2bfloat16(a);
    }
}

__global__ __launch_bounds__(256, 4)
void conv_kernel(const float* __restrict__ x, const float* __restrict__ cw,
                 __hip_bfloat16* __restrict__ h0b) {
    const int tid  = threadIdx.x;
    const int half = tid >> 7;                         // wave-uniform (waves 0-1 / 2-3)
    const int u    = blockIdx.x * 128 + (tid & 127);   // (r,i) task id
    const int i    = u % 26;
    const int r    = u / 26;
    const float c00 = cw[0], c01 = cw[1], c02 = cw[2];
    const float c10 = cw[3], c11 = cw[4], c12 = cw[5];
    const float c20 = cw[6], c21 = cw[7], c22 = cw[8];
    const float* xr = x + (size_t)r * 784 + i * 28;
    __hip_bfloat16* hp = h0b + (size_t)r * 704 + i * 26 + half * 13;
    if (half == 0) conv_body<0>(xr, hp, c00, c01, c02, c10, c11, c12, c20, c21, c22);
    else           conv_body<1>(xr, hp, c00, c01, c02, c10, c11, c12, c20, c21, c22);
    // K-pad cols 676..703 -> zeros (one writer per image)
    if (half == 1 && i == 25) {
        uint* pz = (uint*)(h0b + (size_t)r * 704 + 676);   // byte 1352: 4B aligned
        #pragma unroll
        for (int q = 0; q < 14; q++) pz[q] = 0u;
    }
}

// ---------------------------------------------------------------------------
// Split path, kernel B: h0b[64 rows] -> GEMM1(LDS-staged B panels) -> GEMM2 -> GEMM3.
// 256 threads / 4 waves. LDS 51200B: [bpan 16KB | h2s overlays][h1s 33792].
__global__ __launch_bounds__(256, 2)
void gemm_kernel(const __hip_bfloat16* __restrict__ h0b,
                 const __hip_bfloat16* __restrict__ w1b, const float* __restrict__ b1,
                 const __hip_bfloat16* __restrict__ w2b, const float* __restrict__ b2,
                 const __hip_bfloat16* __restrict__ w3b, const float* __restrict__ b3,
                 float* __restrict__ out) {
    __shared__ __align__(16) char smem[17408 + GM * H1S * 2];  // 51200B
    char* bpan = smem;                                   // GEMM1 B panel (16KB)
    __hip_bfloat16* h2s = (__hip_bfloat16*)smem;         // overlays bpan after GEMM1
    __hip_bfloat16* h1s = (__hip_bfloat16*)(smem + 17408);

    const int tid  = threadIdx.x;
    const int r0   = blockIdx.x * GM;
    const int wave = tid >> 6;
    const int lane = tid & 63;
    const int l15  = lane & 15;
    const int g    = lane >> 4;
    const char* w1c = (const char*)w1b;

    // ---- GEMM1: h1 = relu(h0 @ w1 + b1), M=64 N=256 K=704 ----
    // wave -> (mhalf = wave>>1, nhalf = wave&1): 32 rows x 128 cols.
    // B: one 16KB panel per kc staged to LDS (reg double-issue: load next panel
    //    before compute, write after barrier). ds_reads swizzled -> <=2-way banks.
    // A: streamed from h0b with a 4-slot ring (distance 3) to cover HBM latency.
    {
        const int mh = wave >> 1, nh = wave & 1;
        const __hip_bfloat16* arow0 = h0b + (size_t)(r0 + mh * 32 + l15) * 704;
        const __hip_bfloat16* arow1 = arow0 + (size_t)16 * 704;

        float4 st[4];
        #pragma unroll
        for (int j = 0; j < 4; j++)
            st[j] = *(const float4*)(w1c + 0 * PANEL_B + j * 4096 + tid * 16);
        #pragma unroll
        for (int j = 0; j < 4; j++)
            *(float4*)(bpan + j * 4096 + tid * 16) = st[j];    // lane-linear: 2-way banks

        bf16x8 ar[4][2];
        #pragma unroll
        for (int p = 0; p < 3; p++) {
            ar[p][0] = *(const bf16x8*)(arow0 + p * 32 + g * 8);
            ar[p][1] = *(const bf16x8*)(arow1 + p * 32 + g * 8);
        }
        f32x4 acc[2][8];
        #pragma unroll
        for (int mt = 0; mt < 2; mt++)
            #pragma unroll
            for (int nt = 0; nt < 8; nt++)
                acc[mt][nt] = (f32x4){0.f, 0.f, 0.f, 0.f};
        __syncthreads();                                   // panel 0 visible

        #pragma unroll
        for (int kc = 0; kc < KC1; kc++) {
            if (kc + 1 < KC1) {                            // issue next panel loads
                #pragma unroll
                for (int j = 0; j < 4; j++)
                    st[j] = *(const float4*)(w1c + (size_t)(kc + 1) * PANEL_B + j * 4096 + tid * 16);
            }
            if (kc + 3 < KC1) {                            // A ring: load kc+3
                const int sl = (kc + 3) & 3;
                ar[sl][0] = *(const bf16x8*)(arow0 + (kc + 3) * 32 + g * 8);
                ar[sl][1] = *(const bf16x8*)(arow1 + (kc + 3) * 32 + g * 8);
            }
            bf16x8 bb[8];
            #pragma unroll
            for (int nt = 0; nt < 8; nt++) {
                const int n = nh * 128 + nt * 16 + l15;
                const int off = (n * 64 + g * 16) ^ ((n & 7) << 4);
                bb[nt] = *(const bf16x8*)(bpan + off);
            }
            const int cs = kc & 3;
            #pragma unroll
            for (int mt = 0; mt < 2; mt++)
                #pragma unroll
                for (int nt = 0; nt < 8; nt++)
                    acc[mt][nt] = __builtin_amdgcn_mfma_f32_16x16x32_bf16(
                        ar[cs][mt], bb[nt], acc[mt][nt], 0, 0, 0);
            __syncthreads();                               // everyone done reading panel
            if (kc + 1 < KC1) {
                #pragma unroll
                for (int j = 0; j < 4; j++)
                    *(float4*)(bpan + j * 4096 + tid * 16) = st[j];
                __syncthreads();                           // panel kc+1 visible
            }
        }
        #pragma unroll
        for (int nt = 0; nt < 8; nt++) {
            const int n = nh * 128 + nt * 16 + l15;
            const float bias = b1[n];
            #pragma unroll
            for (int mt = 0; mt < 2; mt++) {
                #pragma unroll
                for (int q = 0; q < 4; q++) {
                    const int row = mh * 32 + mt * 16 + g * 4 + q;  // C/D: col=l15, row=g*4+q
                    float v = acc[mt][nt][q] + bias;
                    h1s[row * H1S + n] = __float2bfloat16(fmaxf(v, 0.0f));
                }
            }
        }
    }
    __syncthreads();

    // ---- GEMM2: h2 = relu(h1 @ w2 + b2), M=64 N=128 K=256 ----
    // wave owns N=32 slice, all 64 rows. B from L2 (w2b hot, 64KB), dist-2 ring.
    {
        f32x4 acc[4][2];
        #pragma unroll
        for (int mt = 0; mt < 4; mt++)
            #pragma unroll
            for (int nt = 0; nt < 2; nt++)
                acc[mt][nt] = (f32x4){0.f, 0.f, 0.f, 0.f};
        const int nb = wave * 32;
        bf16x8 bb2[3][2];
        #pragma unroll
        for (int p = 0; p < 2; p++)
            #pragma unroll
            for (int nt = 0; nt < 2; nt++)
                bb2[p][nt] = *(const bf16x8*)(w2b + ((p * 128 + nb + nt * 16 + l15) * 32 + g * 8));
        #pragma unroll
        for (int kc = 0; kc < KC2; kc++) {
            const int cur = kc % 3, nxt = (kc + 2) % 3;
            if (kc + 2 < KC2) {
                #pragma unroll
                for (int nt = 0; nt < 2; nt++)
                    bb2[nxt][nt] = *(const bf16x8*)(w2b + (((kc + 2) * 128 + nb + nt * 16 + l15) * 32 + g * 8));
            }
            bf16x8 ab[4];
            #pragma unroll
            for (int mt = 0; mt < 4; mt++)
                ab[mt] = *(const bf16x8*)(h1s + (mt * 16 + l15) * H1S + kc * 32 + g * 8);
            #pragma unroll
            for (int mt = 0; mt < 4; mt++)
                #pragma unroll
                for (int nt = 0; nt < 2; nt++)
                    acc[mt][nt] = __builtin_amdgcn_mfma_f32_16x16x32_bf16(
                        ab[mt], bb2[cur][nt], acc[mt][nt], 0, 0, 0);
        }
        #pragma unroll
        for (int nt = 0; nt < 2; nt++) {
            const int n = nb + nt * 16 + l15;
            const float bias = b2[n];
            #pragma unroll
            for (int mt = 0; mt < 4; mt++) {
                #pragma unroll
                for (int q = 0; q < 4; q++) {
                    const int row = mt * 16 + g * 4 + q;
                    float v = acc[mt][nt][q] + bias;
                    h2s[row * H2S + n] = __float2bfloat16(fmaxf(v, 0.0f));  // overlays bpan (dead)
                }
            }
        }
    }
    __syncthreads();

    // ---- GEMM3: out = h2 @ w3 + b3, M=64 N=16(10) K=128; 4 waves x 16 rows ----
    {
        f32x4 acc3 = (f32x4){0.f, 0.f, 0.f, 0.f};
        #pragma unroll
        for (int kc = 0; kc < KC3; kc++) {
            bf16x8 a = *(const bf16x8*)(h2s + (wave * 16 + l15) * H2S + kc * 32 + g * 8);
            bf16x8 b = *(const bf16x8*)(w3b + ((kc * 16 + l15) * 32 + g * 8));
            acc3 = __builtin_amdgcn_mfma_f32_16x16x32_bf16(a, b, acc3, 0, 0, 0);
        }
        if (l15 < 10) {
            const float bias = b3[l15];
            #pragma unroll
            for (int q = 0; q < 4; q++) {
                const int row = wave * 16 + g * 4 + q;
                out[(size_t)(r0 + row) * 10 + l15] = acc3[q] + bias;
            }
        }
    }
}

// ---------------------------------------------------------------------------
// Fallback: R3 fused kernel (proven 129us), adapted to the swizzled w1b layout.
__global__ __launch_bounds__(256, 2)
void fused_model(const float* __restrict__ x, const float* __restrict__ cw,
                 const __hip_bfloat16* __restrict__ w1b, const float* __restrict__ b1,
                 const __hip_bfloat16* __restrict__ w2b, const float* __restrict__ b2,
                 const __hip_bfloat16* __restrict__ w3b, const float* __restrict__ b3,
                 float* __restrict__ out) {
    __shared__ __align__(16) char smem[MR * H0S * 2 + MR * H1S * 2];
    __hip_bfloat16* h0s = (__hip_bfloat16*)smem;
    __hip_bfloat16* h1s = (__hip_bfloat16*)(smem + MR * H0S * 2);
    __hip_bfloat16* h2s = (__hip_bfloat16*)smem;
    const char* w1c = (const char*)w1b;

    const int tid = threadIdx.x;
    const int r0  = blockIdx.x * MR;

    const float c00 = cw[0], c01 = cw[1], c02 = cw[2];
    const float c10 = cw[3], c11 = cw[4], c12 = cw[5];
    const float c20 = cw[6], c21 = cw[7], c22 = cw[8];

    for (int t = tid; t < MR * 26; t += 256) {
        int r = t / 26;
        int i = t - r * 26;
        const float* xr = x + (size_t)(r0 + r) * 784 + i * 28;
        float4 v[21];
        #pragma unroll
        for (int di = 0; di < 3; di++) {
            const float4* p4 = (const float4*)(xr + di * 28);
            #pragma unroll
            for (int q = 0; q < 7; q++) v[di * 7 + q] = p4[q];
        }
        #pragma unroll
        for (int k = 0; k < 21; k++)
            asm volatile("" :: "v"(v[k].x), "v"(v[k].y), "v"(v[k].z), "v"(v[k].w));
        float rb[3][28];
        #pragma unroll
        for (int di = 0; di < 3; di++) {
            #pragma unroll
            for (int q = 0; q < 7; q++) {
                rb[di][q*4+0] = v[di*7+q].x; rb[di][q*4+1] = v[di*7+q].y;
                rb[di][q*4+2] = v[di*7+q].z; rb[di][q*4+3] = v[di*7+q].w;
            }
        }
        __hip_bfloat162* hp = (__hip_bfloat162*)(h0s + r * H0S + i * 26);
        #pragma unroll
        for (int k = 0; k < 13; k++) {
            const int j0 = 2 * k, j1 = 2 * k + 1;
            float a0 = c00*rb[0][j0] + c01*rb[0][j0+1] + c02*rb[0][j0+2]
                     + c10*rb[1][j0] + c11*rb[1][j0+1] + c12*rb[1][j0+2]
                     + c20*rb[2][j0] + c21*rb[2][j0+1] + c22*rb[2][j0+2];
            float a1 = c00*rb[0][j1] + c01*rb[0][j1+1] + c02*rb[0][j1+2]
                     + c10*rb[1][j1] + c11*rb[1][j1+1] + c12*rb[1][j1+2]
                     + c20*rb[2][j1] + c21*rb[2][j1+1] + c22*rb[2][j1+2];
            __hip_bfloat162 pr;
            pr.x = __float2bfloat16(a0);
            pr.y = __float2bfloat16(a1);
            hp[k] = pr;
        }
    }
    for (int t = tid; t < MR * 18; t += 256) {
        int r = t / 18;
        int c = t - r * 18;
        ((uint*)(h0s + r * H0S + 676))[c] = 0u;
    }
    __syncthreads();

    const int wave = tid >> 6;
    const int lane = tid & 63;
    const int l15  = lane & 15;
    const int g    = lane >> 4;

    {   // GEMM1 (w1b swizzled addressing)
        f32x4 acc[2][4];
        #pragma unroll
        for (int mt = 0; mt < 2; mt++)
            #pragma unroll
            for (int nt = 0; nt < 4; nt++)
                acc[mt][nt] = (f32x4){0.f, 0.f, 0.f, 0.f};
        const int nb = wave * 64;
        bf16x8 ab[3][2], bb[3][4];
        #pragma unroll
        for (int p = 0; p < 2; p++) {
            #pragma unroll
            for (int mt = 0; mt < 2; mt++)
                ab[p][mt] = *(const bf16x8*)(h0s + (mt * 16 + l15) * H0S + p * 32 + g * 8);
            #pragma unroll
            for (int nt = 0; nt < 4; nt++) {
                const int n = nb + nt * 16 + l15;
                bb[p][nt] = *(const bf16x8*)(w1c + (size_t)p * PANEL_B
                                + ((n * 64 + g * 16) ^ ((n & 7) << 4)));
            }
        }
        #pragma unroll
        for (int kc = 0; kc < KC1; kc++) {
            const int cur = kc % 3;
            const int nxt = (kc + 2) % 3;
            if (kc + 2 < KC1) {
                #pragma unroll
                for (int mt = 0; mt < 2; mt++)
                    ab[nxt][mt] = *(const bf16x8*)(h0s + (mt * 16 + l15) * H0S + (kc + 2) * 32 + g * 8);
                #pragma unroll
                for (int nt = 0; nt < 4; nt++) {
                    const int n = nb + nt * 16 + l15;
                    bb[nxt][nt] = *(const bf16x8*)(w1c + (size_t)(kc + 2) * PANEL_B
                                    + ((n * 64 + g * 16) ^ ((n & 7) << 4)));
                }
            }
            #pragma unroll
            for (int mt = 0; mt < 2; mt++)
                #pragma unroll
                for (int nt = 0; nt < 4; nt++)
                    acc[mt][nt] = __builtin_amdgcn_mfma_f32_16x16x32_bf16(
                        ab[cur][mt], bb[cur][nt], acc[mt][nt], 0, 0, 0);
        }
        #pragma unroll
        for (int nt = 0; nt < 4; nt++) {
            const int n = nb + nt * 16 + l15;
            const float bias = b1[n];
            #pragma unroll
            for (int mt = 0; mt < 2; mt++) {
                #pragma unroll
                for (int q = 0; q < 4; q++) {
                    const int row = mt * 16 + g * 4 + q;
                    float v = acc[mt][nt][q] + bias;
                    h1s[row * H1S + n] = __float2bfloat16(fmaxf(v, 0.0f));
                }
            }
        }
    }
    __syncthreads();

    {   // GEMM2
        f32x4 acc[2][2];
        #pragma unroll
        for (int mt = 0; mt < 2; mt++)
            #pragma unroll
            for (int nt = 0; nt < 2; nt++)
                acc[mt][nt] = (f32x4){0.f, 0.f, 0.f, 0.f};
        const int nb = wave * 32;
        bf16x8 ab[3][2], bb[3][2];
        #pragma unroll
        for (int p = 0; p < 2; p++) {
            #pragma unroll
            for (int mt = 0; mt < 2; mt++)
                ab[p][mt] = *(const bf16x8*)(h1s + (mt * 16 + l15) * H1S + p * 32 + g * 8);
            #pragma unroll
            for (int nt = 0; nt < 2; nt++)
                bb[p][nt] = *(const bf16x8*)(w2b + ((p * 128 + nb + nt * 16 + l15) * 32 + g * 8));
        }
        #pragma unroll
        for (int kc = 0; kc < KC2; kc++) {
            const int cur = kc % 3;
            const int nxt = (kc + 2) % 3;
            if (kc + 2 < KC2) {
                #pragma unroll
                for (int mt = 0; mt < 2; mt++)
                    ab[nxt][mt] = *(const bf16x8*)(h1s + (mt * 16 + l15) * H1S + (kc + 2) * 32 + g * 8);
                #pragma unroll
                for (int nt = 0; nt < 2; nt++)
                    bb[nxt][nt] = *(const bf16x8*)(w2b + (((kc + 2) * 128 + nb + nt * 16 + l15) * 32 + g * 8));
            }
            #pragma unroll
            for (int mt = 0; mt < 2; mt++)
                #pragma unroll
                for (int nt = 0; nt < 2; nt++)
                    acc[mt][nt] = __builtin_amdgcn_mfma_f32_16x16x32_bf16(
                        ab[cur][mt], bb[cur][nt], acc[mt][nt], 0, 0, 0);
        }
        #pragma unroll
        for (int nt = 0; nt < 2; nt++) {
            const int n = nb + nt * 16 + l15;
            const float bias = b2[n];
            #pragma unroll
            for (int mt = 0; mt < 2; mt++) {
                #pragma unroll
                for (int q = 0; q < 4; q++) {
                    const int row = mt * 16 + g * 4 + q;
                    float v = acc[mt][nt][q] + bias;
                    h2s[row * H2S + n] = __float2bfloat16(fmaxf(v, 0.0f));
                }
            }
        }
    }
    __syncthreads();

    if (wave < 2) {  // GEMM3
        f32x4 acc3 = (f32x4){0.f, 0.f, 0.f, 0.f};
        #pragma unroll
        for (int kc = 0; kc < KC3; kc++) {
            bf16x8 a = *(const bf16x8*)(h2s + (wave * 16 + l15) * H2S + kc * 32 + g * 8);
            bf16x8 b = *(const bf16x8*)(w3b + ((kc * 16 + l15) * 32 + g * 8));
            acc3 = __builtin_amdgcn_mfma_f32_16x16x32_bf16(a, b, acc3, 0, 0, 0);
        }
        if (l15 < 10) {
            const float bias = b3[l15];
            #pragma unroll
            for (int q = 0; q < 4; q++) {
                const int row = wave * 16 + g * 4 + q;
                out[(size_t)(r0 + row) * 10 + l15] = acc3[q] + bias;
            }
        }
    }
}

extern "C" void kernel_launch(void* const* d_in, const int* in_sizes, int n_in,
                              void* d_out, int out_size, void* d_ws, size_t ws_size,
                              hipStream_t stream) {
    const float* x  = (const float*)d_in[0];
    const float* cw = (const float*)d_in[1];
    const float* w1 = (const float*)d_in[2];
    const float* b1 = (const float*)d_in[3];
    const float* w2 = (const float*)d_in[4];
    const float* b2 = (const float*)d_in[5];
    const float* w3 = (const float*)d_in[6];
    const float* b3 = (const float*)d_in[7];
    float* out = (float*)d_out;

    __hip_bfloat16* w1b = (__hip_bfloat16*)d_ws;
    __hip_bfloat16* w2b = (__hip_bfloat16*)((char*)d_ws + W1B_BYTES);
    __hip_bfloat16* w3b = w2b + W2B_ELEMS;

    const int pack_total = W1B_ELEMS + W2B_ELEMS + W3B_ELEMS;  // 215040
    pack_weights<<<(pack_total + 255) / 256, 256, 0, stream>>>(w1, w2, w3, w1b, w2b, w3b);

    const size_t need = (size_t)WS_WEIGHTS + H0B_BYTES;
    if (ws_size >= need) {
        __hip_bfloat16* h0b = (__hip_bfloat16*)((char*)d_ws + WS_WEIGHTS);
        conv_kernel<<<B_ROWS * 26 / 128, 256, 0, stream>>>(x, cw, h0b);
        gemm_kernel<<<B_ROWS / GM, 256, 0, stream>>>(h0b, w1b, b1, w2b, b2, w3b, b3, out);
    } else {
        fused_model<<<B_ROWS / MR, 256, 0, stream>>>(x, cw, w1b, b1, w2b, b2, w3b, b3, out);
    }
}

// Round 8
// 439.394 us; speedup vs baseline: 1.0162x; 1.0162x over previous
//
#include <hip/hip_runtime.h>
#include <hip/hip_bf16.h>

typedef __bf16 bf16x8 __attribute__((ext_vector_type(8)));
typedef float  f32x4  __attribute__((ext_vector_type(4)));
typedef union { float4 f; bf16x8 b; } frag_t;   // load as float4 (pinnable), use as bf16x8

#define PIN4(v) asm volatile("" :: "v"((v).x), "v"((v).y), "v"((v).z), "v"((v).w))

#define B_ROWS 65536
#define KC1 22           // 704/32
#define KC2 8            // 256/32
#define KC3 4            // 128/32
#define H1S 264          // h1 LDS stride (256+8 pad)
#define H2S 136          // h2 LDS stride (128+8 pad)
#define W1B_ELEMS (704*256)
#define W2B_ELEMS (256*128)
#define W3B_ELEMS (128*16)
#define WS_WEIGHTS ((W1B_ELEMS + W2B_ELEMS + W3B_ELEMS) * 2)
#define H0B_BYTES ((size_t)B_ROWS*704*2)                // 92.3MB
#define GM 32            // rows per gemm block

// fused-fallback geometry (R3)
#define MR 32
#define H0S 712

// ---------------------------------------------------------------------------
// Pack weights to bf16 in MFMA-B layout [kc][n][ki(32)] (linear, R3 layout).
__global__ void pack_weights(const float* __restrict__ w1,
                             const float* __restrict__ w2,
                             const float* __restrict__ w3,
                             __hip_bfloat16* __restrict__ w1b,
                             __hip_bfloat16* __restrict__ w2b,
                             __hip_bfloat16* __restrict__ w3b) {
    int idx = blockIdx.x * 256 + threadIdx.x;
    if (idx < W1B_ELEMS) {
        int ki = idx & 31, t = idx >> 5;
        int n = t & 255, kc = t >> 8;
        int k = kc * 32 + ki;
        float v = (k < 676) ? w1[k * 256 + n] : 0.0f;   // zero-pad K 676->704
        w1b[idx] = __float2bfloat16(v);
    } else if (idx < W1B_ELEMS + W2B_ELEMS) {
        int j = idx - W1B_ELEMS;
        int ki = j & 31, t = j >> 5;
        int n = t & 127, kc = t >> 7;
        w2b[j] = __float2bfloat16(w2[(kc * 32 + ki) * 128 + n]);
    } else if (idx < W1B_ELEMS + W2B_ELEMS + W3B_ELEMS) {
        int j = idx - W1B_ELEMS - W2B_ELEMS;
        int ki = j & 31, t = j >> 5;
        int n = t & 15, kc = t >> 4;
        float v = (n < 10) ? w3[(kc * 32 + ki) * 10 + n] : 0.0f;  // zero-pad N 10->16
        w3b[j] = __float2bfloat16(v);
    }
}

// ---------------------------------------------------------------------------
// Kernel A: conv3x3 valid, fp32 exact, h0b[r][704] bf16 to global. (R7, proven)
template<int S>
__device__ __forceinline__ void conv_body(
        const float* __restrict__ xr, __hip_bfloat16* __restrict__ hp,
        float c00, float c01, float c02, float c10, float c11, float c12,
        float c20, float c21, float c22) {
    float4 v[3][4];
    #pragma unroll
    for (int d = 0; d < 3; d++) {
        const float4* p4 = (const float4*)(xr + d * 28);   // rows 112B -> 16B aligned
        #pragma unroll
        for (int q = 0; q < 4; q++) v[d][q] = p4[S * 3 + q];
    }
    #pragma unroll
    for (int d = 0; d < 3; d++)
        #pragma unroll
        for (int q = 0; q < 4; q++) PIN4(v[d][q]);
    float rb[3][16];
    #pragma unroll
    for (int d = 0; d < 3; d++)
        #pragma unroll
        for (int q = 0; q < 4; q++) {
            rb[d][q*4+0] = v[d][q].x; rb[d][q*4+1] = v[d][q].y;
            rb[d][q*4+2] = v[d][q].z; rb[d][q*4+3] = v[d][q].w;
        }
    #pragma unroll
    for (int jj = 0; jj < 13; jj++) {
        float a = c00*rb[0][S+jj] + c01*rb[0][S+jj+1] + c02*rb[0][S+jj+2]
                + c10*rb[1][S+jj] + c11*rb[1][S+jj+1] + c12*rb[1][S+jj+2]
                + c20*rb[2][S+jj] + c21*rb[2][S+jj+1] + c22*rb[2][S+jj+2];
        hp[jj] = __float2bfloat16(a);
    }
}

__global__ __launch_bounds__(256, 4)
void conv_kernel(const float* __restrict__ x, const float* __restrict__ cw,
                 __hip_bfloat16* __restrict__ h0b) {
    const int tid  = threadIdx.x;
    const int half = tid >> 7;                         // wave-uniform (waves 0-1 / 2-3)
    const int u    = blockIdx.x * 128 + (tid & 127);   // (r,i) task id
    const int i    = u % 26;
    const int r    = u / 26;
    const float c00 = cw[0], c01 = cw[1], c02 = cw[2];
    const float c10 = cw[3], c11 = cw[4], c12 = cw[5];
    const float c20 = cw[6], c21 = cw[7], c22 = cw[8];
    const float* xr = x + (size_t)r * 784 + i * 28;
    __hip_bfloat16* hp = h0b + (size_t)r * 704 + i * 26 + half * 13;
    if (half == 0) conv_body<0>(xr, hp, c00, c01, c02, c10, c11, c12, c20, c21, c22);
    else           conv_body<1>(xr, hp, c00, c01, c02, c10, c11, c12, c20, c21, c22);
    // K-pad cols 676..703 -> zeros (one writer per image)
    if (half == 1 && i == 25) {
        uint* pz = (uint*)(h0b + (size_t)r * 704 + 676);   // byte 1352: 4B aligned
        #pragma unroll
        for (int q = 0; q < 14; q++) pz[q] = 0u;
    }
}

// ---------------------------------------------------------------------------
// Kernel B v2: R3-proven GEMM structure, zero barriers in K-loops, no A/B LDS.
// GM=32 rows/block, 4 waves, wave = 32 rows x 64 cols (nt=4). A direct from
// h0b global (pinned dist-2 ring), B direct from L2 (pinned dist-2 ring).
// LDS 25.6KB (h1+h2 only) -> 4 blocks/CU at VGPR<=128 = 16 waves/CU: TLP and
// MLP together (R1/R5 lesson), with barriers only at phase handoffs.
__global__ __launch_bounds__(256, 4)
void gemm_kernel(const __hip_bfloat16* __restrict__ h0b,
                 const __hip_bfloat16* __restrict__ w1b, const float* __restrict__ b1,
                 const __hip_bfloat16* __restrict__ w2b, const float* __restrict__ b2,
                 const __hip_bfloat16* __restrict__ w3b, const float* __restrict__ b3,
                 float* __restrict__ out) {
    __shared__ __align__(16) char smem[GM * H1S * 2 + GM * H2S * 2];  // 25600B
    __hip_bfloat16* h1s = (__hip_bfloat16*)smem;
    __hip_bfloat16* h2s = (__hip_bfloat16*)(smem + GM * H1S * 2);

    const int tid  = threadIdx.x;
    const int r0   = blockIdx.x * GM;
    const int wave = tid >> 6;
    const int lane = tid & 63;
    const int l15  = lane & 15;
    const int g    = lane >> 4;

    // ---- GEMM1: h1 = relu(h0 @ w1 + b1), M=32 N=256 K=704 ----
    {
        f32x4 acc[2][4];
        #pragma unroll
        for (int mt = 0; mt < 2; mt++)
            #pragma unroll
            for (int nt = 0; nt < 4; nt++)
                acc[mt][nt] = (f32x4){0.f, 0.f, 0.f, 0.f};
        const int nb = wave * 64;
        const __hip_bfloat16* a0 = h0b + (size_t)(r0 + l15) * 704 + g * 8;
        const __hip_bfloat16* a1 = h0b + (size_t)(r0 + 16 + l15) * 704 + g * 8;
        frag_t ab[3][2], bb[3][4];
        #pragma unroll
        for (int p = 0; p < 2; p++) {
            ab[p][0].f = *(const float4*)(a0 + p * 32);
            ab[p][1].f = *(const float4*)(a1 + p * 32);
            PIN4(ab[p][0].f); PIN4(ab[p][1].f);
            #pragma unroll
            for (int nt = 0; nt < 4; nt++) {
                bb[p][nt].f = *(const float4*)(w1b + ((p * 256 + nb + nt * 16 + l15) * 32 + g * 8));
                PIN4(bb[p][nt].f);
            }
        }
        #pragma unroll
        for (int kc = 0; kc < KC1; kc++) {
            const int cur = kc % 3;
            const int nxt = (kc + 2) % 3;
            if (kc + 2 < KC1) {
                ab[nxt][0].f = *(const float4*)(a0 + (kc + 2) * 32);
                ab[nxt][1].f = *(const float4*)(a1 + (kc + 2) * 32);
                PIN4(ab[nxt][0].f); PIN4(ab[nxt][1].f);
                #pragma unroll
                for (int nt = 0; nt < 4; nt++) {
                    bb[nxt][nt].f = *(const float4*)(w1b + (((kc + 2) * 256 + nb + nt * 16 + l15) * 32 + g * 8));
                    PIN4(bb[nxt][nt].f);
                }
            }
            #pragma unroll
            for (int mt = 0; mt < 2; mt++)
                #pragma unroll
                for (int nt = 0; nt < 4; nt++)
                    acc[mt][nt] = __builtin_amdgcn_mfma_f32_16x16x32_bf16(
                        ab[cur][mt].b, bb[cur][nt].b, acc[mt][nt], 0, 0, 0);
        }
        #pragma unroll
        for (int nt = 0; nt < 4; nt++) {
            const int n = nb + nt * 16 + l15;
            const float bias = b1[n];
            #pragma unroll
            for (int mt = 0; mt < 2; mt++) {
                #pragma unroll
                for (int q = 0; q < 4; q++) {
                    const int row = mt * 16 + g * 4 + q;   // C/D: col=lane&15, row=(lane>>4)*4+q
                    float v = acc[mt][nt][q] + bias;
                    h1s[row * H1S + n] = __float2bfloat16(fmaxf(v, 0.0f));
                }
            }
        }
    }
    __syncthreads();

    // ---- GEMM2: h2 = relu(h1 @ w2 + b2), M=32 N=128 K=256 ----
    {
        f32x4 acc[2][2];
        #pragma unroll
        for (int mt = 0; mt < 2; mt++)
            #pragma unroll
            for (int nt = 0; nt < 2; nt++)
                acc[mt][nt] = (f32x4){0.f, 0.f, 0.f, 0.f};
        const int nb = wave * 32;
        frag_t ab[3][2], bb[3][2];
        #pragma unroll
        for (int p = 0; p < 2; p++) {
            #pragma unroll
            for (int mt = 0; mt < 2; mt++)
                ab[p][mt].f = *(const float4*)(h1s + (mt * 16 + l15) * H1S + p * 32 + g * 8);
            #pragma unroll
            for (int nt = 0; nt < 2; nt++) {
                bb[p][nt].f = *(const float4*)(w2b + ((p * 128 + nb + nt * 16 + l15) * 32 + g * 8));
                PIN4(bb[p][nt].f);
            }
        }
        #pragma unroll
        for (int kc = 0; kc < KC2; kc++) {
            const int cur = kc % 3;
            const int nxt = (kc + 2) % 3;
            if (kc + 2 < KC2) {
                #pragma unroll
                for (int mt = 0; mt < 2; mt++)
                    ab[nxt][mt].f = *(const float4*)(h1s + (mt * 16 + l15) * H1S + (kc + 2) * 32 + g * 8);
                #pragma unroll
                for (int nt = 0; nt < 2; nt++) {
                    bb[nxt][nt].f = *(const float4*)(w2b + (((kc + 2) * 128 + nb + nt * 16 + l15) * 32 + g * 8));
                    PIN4(bb[nxt][nt].f);
                }
            }
            #pragma unroll
            for (int mt = 0; mt < 2; mt++)
                #pragma unroll
                for (int nt = 0; nt < 2; nt++)
                    acc[mt][nt] = __builtin_amdgcn_mfma_f32_16x16x32_bf16(
                        ab[cur][mt].b, bb[cur][nt].b, acc[mt][nt], 0, 0, 0);
        }
        #pragma unroll
        for (int nt = 0; nt < 2; nt++) {
            const int n = nb + nt * 16 + l15;
            const float bias = b2[n];
            #pragma unroll
            for (int mt = 0; mt < 2; mt++) {
                #pragma unroll
                for (int q = 0; q < 4; q++) {
                    const int row = mt * 16 + g * 4 + q;
                    float v = acc[mt][nt][q] + bias;
                    h2s[row * H2S + n] = __float2bfloat16(fmaxf(v, 0.0f));
                }
            }
        }
    }
    __syncthreads();

    // ---- GEMM3: out = h2 @ w3 + b3, M=32 N=16(10) K=128 ----
    if (wave < 2) {
        f32x4 acc3 = (f32x4){0.f, 0.f, 0.f, 0.f};
        #pragma unroll
        for (int kc = 0; kc < KC3; kc++) {
            bf16x8 a = *(const bf16x8*)(h2s + (wave * 16 + l15) * H2S + kc * 32 + g * 8);
            bf16x8 b = *(const bf16x8*)(w3b + ((kc * 16 + l15) * 32 + g * 8));
            acc3 = __builtin_amdgcn_mfma_f32_16x16x32_bf16(a, b, acc3, 0, 0, 0);
        }
        if (l15 < 10) {
            const float bias = b3[l15];
            #pragma unroll
            for (int q = 0; q < 4; q++) {
                const int row = wave * 16 + g * 4 + q;
                out[(size_t)(r0 + row) * 10 + l15] = acc3[q] + bias;
            }
        }
    }
}

// ---------------------------------------------------------------------------
// Fallback: R3 fused kernel (proven), linear w1b layout.
__global__ __launch_bounds__(256, 2)
void fused_model(const float* __restrict__ x, const float* __restrict__ cw,
                 const __hip_bfloat16* __restrict__ w1b, const float* __restrict__ b1,
                 const __hip_bfloat16* __restrict__ w2b, const float* __restrict__ b2,
                 const __hip_bfloat16* __restrict__ w3b, const float* __restrict__ b3,
                 float* __restrict__ out) {
    __shared__ __align__(16) char smem[MR * H0S * 2 + MR * H1S * 2];
    __hip_bfloat16* h0s = (__hip_bfloat16*)smem;
    __hip_bfloat16* h1s = (__hip_bfloat16*)(smem + MR * H0S * 2);
    __hip_bfloat16* h2s = (__hip_bfloat16*)smem;

    const int tid = threadIdx.x;
    const int r0  = blockIdx.x * MR;

    const float c00 = cw[0], c01 = cw[1], c02 = cw[2];
    const float c10 = cw[3], c11 = cw[4], c12 = cw[5];
    const float c20 = cw[6], c21 = cw[7], c22 = cw[8];

    for (int t = tid; t < MR * 26; t += 256) {
        int r = t / 26;
        int i = t - r * 26;
        const float* xr = x + (size_t)(r0 + r) * 784 + i * 28;
        float4 v[21];
        #pragma unroll
        for (int di = 0; di < 3; di++) {
            const float4* p4 = (const float4*)(xr + di * 28);
            #pragma unroll
            for (int q = 0; q < 7; q++) v[di * 7 + q] = p4[q];
        }
        #pragma unroll
        for (int k = 0; k < 21; k++) PIN4(v[k]);
        float rb[3][28];
        #pragma unroll
        for (int di = 0; di < 3; di++) {
            #pragma unroll
            for (int q = 0; q < 7; q++) {
                rb[di][q*4+0] = v[di*7+q].x; rb[di][q*4+1] = v[di*7+q].y;
                rb[di][q*4+2] = v[di*7+q].z; rb[di][q*4+3] = v[di*7+q].w;
            }
        }
        __hip_bfloat162* hp = (__hip_bfloat162*)(h0s + r * H0S + i * 26);
        #pragma unroll
        for (int k = 0; k < 13; k++) {
            const int j0 = 2 * k, j1 = 2 * k + 1;
            float a0 = c00*rb[0][j0] + c01*rb[0][j0+1] + c02*rb[0][j0+2]
                     + c10*rb[1][j0] + c11*rb[1][j0+1] + c12*rb[1][j0+2]
                     + c20*rb[2][j0] + c21*rb[2][j0+1] + c22*rb[2][j0+2];
            float a1 = c00*rb[0][j1] + c01*rb[0][j1+1] + c02*rb[0][j1+2]
                     + c10*rb[1][j1] + c11*rb[1][j1+1] + c12*rb[1][j1+2]
                     + c20*rb[2][j1] + c21*rb[2][j1+1] + c22*rb[2][j1+2];
            __hip_bfloat162 pr;
            pr.x = __float2bfloat16(a0);
            pr.y = __float2bfloat16(a1);
            hp[k] = pr;
        }
    }
    for (int t = tid; t < MR * 18; t += 256) {
        int r = t / 18;
        int c = t - r * 18;
        ((uint*)(h0s + r * H0S + 676))[c] = 0u;
    }
    __syncthreads();

    const int wave = tid >> 6;
    const int lane = tid & 63;
    const int l15  = lane & 15;
    const int g    = lane >> 4;

    {   // GEMM1
        f32x4 acc[2][4];
        #pragma unroll
        for (int mt = 0; mt < 2; mt++)
            #pragma unroll
            for (int nt = 0; nt < 4; nt++)
                acc[mt][nt] = (f32x4){0.f, 0.f, 0.f, 0.f};
        const int nb = wave * 64;
        bf16x8 ab[3][2], bb[3][4];
        #pragma unroll
        for (int p = 0; p < 2; p++) {
            #pragma unroll
            for (int mt = 0; mt < 2; mt++)
                ab[p][mt] = *(const bf16x8*)(h0s + (mt * 16 + l15) * H0S + p * 32 + g * 8);
            #pragma unroll
            for (int nt = 0; nt < 4; nt++)
                bb[p][nt] = *(const bf16x8*)(w1b + ((p * 256 + nb + nt * 16 + l15) * 32 + g * 8));
        }
        #pragma unroll
        for (int kc = 0; kc < KC1; kc++) {
            const int cur = kc % 3;
            const int nxt = (kc + 2) % 3;
            if (kc + 2 < KC1) {
                #pragma unroll
                for (int mt = 0; mt < 2; mt++)
                    ab[nxt][mt] = *(const bf16x8*)(h0s + (mt * 16 + l15) * H0S + (kc + 2) * 32 + g * 8);
                #pragma unroll
                for (int nt = 0; nt < 4; nt++)
                    bb[nxt][nt] = *(const bf16x8*)(w1b + (((kc + 2) * 256 + nb + nt * 16 + l15) * 32 + g * 8));
            }
            #pragma unroll
            for (int mt = 0; mt < 2; mt++)
                #pragma unroll
                for (int nt = 0; nt < 4; nt++)
                    acc[mt][nt] = __builtin_amdgcn_mfma_f32_16x16x32_bf16(
                        ab[cur][mt], bb[cur][nt], acc[mt][nt], 0, 0, 0);
        }
        #pragma unroll
        for (int nt = 0; nt < 4; nt++) {
            const int n = nb + nt * 16 + l15;
            const float bias = b1[n];
            #pragma unroll
            for (int mt = 0; mt < 2; mt++) {
                #pragma unroll
                for (int q = 0; q < 4; q++) {
                    const int row = mt * 16 + g * 4 + q;
                    float v = acc[mt][nt][q] + bias;
                    h1s[row * H1S + n] = __float2bfloat16(fmaxf(v, 0.0f));
                }
            }
        }
    }
    __syncthreads();

    {   // GEMM2
        f32x4 acc[2][2];
        #pragma unroll
        for (int mt = 0; mt < 2; mt++)
            #pragma unroll
            for (int nt = 0; nt < 2; nt++)
                acc[mt][nt] = (f32x4){0.f, 0.f, 0.f, 0.f};
        const int nb = wave * 32;
        bf16x8 ab[3][2], bb[3][2];
        #pragma unroll
        for (int p = 0; p < 2; p++) {
            #pragma unroll
            for (int mt = 0; mt < 2; mt++)
                ab[p][mt] = *(const bf16x8*)(h1s + (mt * 16 + l15) * H1S + p * 32 + g * 8);
            #pragma unroll
            for (int nt = 0; nt < 2; nt++)
                bb[p][nt] = *(const bf16x8*)(w2b + ((p * 128 + nb + nt * 16 + l15) * 32 + g * 8));
        }
        #pragma unroll
        for (int kc = 0; kc < KC2; kc++) {
            const int cur = kc % 3;
            const int nxt = (kc + 2) % 3;
            if (kc + 2 < KC2) {
                #pragma unroll
                for (int mt = 0; mt < 2; mt++)
                    ab[nxt][mt] = *(const bf16x8*)(h1s + (mt * 16 + l15) * H1S + (kc + 2) * 32 + g * 8);
                #pragma unroll
                for (int nt = 0; nt < 2; nt++)
                    bb[nxt][nt] = *(const bf16x8*)(w2b + (((kc + 2) * 128 + nb + nt * 16 + l15) * 32 + g * 8));
            }
            #pragma unroll
            for (int mt = 0; mt < 2; mt++)
                #pragma unroll
                for (int nt = 0; nt < 2; nt++)
                    acc[mt][nt] = __builtin_amdgcn_mfma_f32_16x16x32_bf16(
                        ab[cur][mt], bb[cur][nt], acc[mt][nt], 0, 0, 0);
        }
        #pragma unroll
        for (int nt = 0; nt < 2; nt++) {
            const int n = nb + nt * 16 + l15;
            const float bias = b2[n];
            #pragma unroll
            for (int mt = 0; mt < 2; mt++) {
                #pragma unroll
                for (int q = 0; q < 4; q++) {
                    const int row = mt * 16 + g * 4 + q;
                    float v = acc[mt][nt][q] + bias;
                    h2s[row * H2S + n] = __float2bfloat16(fmaxf(v, 0.0f));
                }
            }
        }
    }
    __syncthreads();

    if (wave < 2) {  // GEMM3
        f32x4 acc3 = (f32x4){0.f, 0.f, 0.f, 0.f};
        #pragma unroll
        for (int kc = 0; kc < KC3; kc++) {
            bf16x8 a = *(const bf16x8*)(h2s + (wave * 16 + l15) * H2S + kc * 32 + g * 8);
            bf16x8 b = *(const bf16x8*)(w3b + ((kc * 16 + l15) * 32 + g * 8));
            acc3 = __builtin_amdgcn_mfma_f32_16x16x32_bf16(a, b, acc3, 0, 0, 0);
        }
        if (l15 < 10) {
            const float bias = b3[l15];
            #pragma unroll
            for (int q = 0; q < 4; q++) {
                const int row = wave * 16 + g * 4 + q;
                out[(size_t)(r0 + row) * 10 + l15] = acc3[q] + bias;
            }
        }
    }
}

extern "C" void kernel_launch(void* const* d_in, const int* in_sizes, int n_in,
                              void* d_out, int out_size, void* d_ws, size_t ws_size,
                              hipStream_t stream) {
    const float* x  = (const float*)d_in[0];
    const float* cw = (const float*)d_in[1];
    const float* w1 = (const float*)d_in[2];
    const float* b1 = (const float*)d_in[3];
    const float* w2 = (const float*)d_in[4];
    const float* b2 = (const float*)d_in[5];
    const float* w3 = (const float*)d_in[6];
    const float* b3 = (const float*)d_in[7];
    float* out = (float*)d_out;

    __hip_bfloat16* w1b = (__hip_bfloat16*)d_ws;
    __hip_bfloat16* w2b = w1b + W1B_ELEMS;
    __hip_bfloat16* w3b = w2b + W2B_ELEMS;

    const int pack_total = W1B_ELEMS + W2B_ELEMS + W3B_ELEMS;  // 215040
    pack_weights<<<(pack_total + 255) / 256, 256, 0, stream>>>(w1, w2, w3, w1b, w2b, w3b);

    const size_t need = (size_t)WS_WEIGHTS + H0B_BYTES;
    if (ws_size >= need) {
        __hip_bfloat16* h0b = (__hip_bfloat16*)((char*)d_ws + WS_WEIGHTS);
        conv_kernel<<<B_ROWS * 26 / 128, 256, 0, stream>>>(x, cw, h0b);
        gemm_kernel<<<B_ROWS / GM, 256, 0, stream>>>(h0b, w1b, b1, w2b, b2, w3b, b3, out);
    } else {
        fused_model<<<B_ROWS / MR, 256, 0, stream>>>(x, cw, w1b, b1, w2b, b2, w3b, b3, out);
    }
}

// Round 9
// 381.045 us; speedup vs baseline: 1.1718x; 1.1531x over previous
//
#include <hip/hip_runtime.h>
#include <hip/hip_bf16.h>
#include <stdint.h>

typedef __bf16 bf16x8 __attribute__((ext_vector_type(8)));
typedef float  f32x4  __attribute__((ext_vector_type(4)));

#define PIN4(v) asm volatile("" :: "v"((v).x), "v"((v).y), "v"((v).z), "v"((v).w))

#define B_ROWS 65536
#define KC1 22           // 704/32
#define KC2 8            // 256/32
#define KC3 4            // 128/32
#define H1S 264          // h1 LDS stride (256+8 pad)
#define H2S 136          // h2 LDS stride (128+8 pad)
#define PANEL_B 16384    // one w1 K-panel: 256 n x 64B (swizzled LDS image)
#define W1B_ELEMS (704*256)
#define W2B_ELEMS (256*128)
#define W3B_ELEMS (128*16)
#define W1B_BYTES (KC1*PANEL_B)                              // 360448
#define WS_WEIGHTS (W1B_BYTES + W2B_ELEMS*2 + W3B_ELEMS*2)   // 430080
#define H0B_BYTES ((size_t)B_ROWS*704*2)                     // 92.3MB
#define GM 64            // rows per gemm block

// fused-fallback geometry (R3)
#define MR 32
#define H0S 712

// ---------------------------------------------------------------------------
// Pack weights to bf16.
// w1b: per-kc 16KB panel stored as the LDS IMAGE for linear global_load_lds
//   staging: element (n, ki=g*8+j) lives at byte kc*16384 + (n*4 + (g^(n&3)))*16 + j*2.
//   After linear staging, a wave's ds_read_b128 of fragment (nt,l15,g) at
//   byte n*64 + (g^(l15&3))*16 hits <=4-way banks instead of 8-way.
// w2b/w3b: [kc][n][ki32] linear (R3 layout).
__global__ void pack_weights(const float* __restrict__ w1,
                             const float* __restrict__ w2,
                             const float* __restrict__ w3,
                             __hip_bfloat16* __restrict__ w1b,
                             __hip_bfloat16* __restrict__ w2b,
                             __hip_bfloat16* __restrict__ w3b) {
    int idx = blockIdx.x * 256 + threadIdx.x;
    if (idx < W1B_ELEMS) {
        int ki = idx & 31, t = idx >> 5;
        int n = t & 255, kc = t >> 8;
        int k = kc * 32 + ki;
        float v = (k < 676) ? w1[k * 256 + n] : 0.0f;   // zero-pad K 676->704
        int gg = ki >> 3, j = ki & 7;
        int u = n * 4 + (gg ^ (n & 3));
        *(__hip_bfloat16*)((char*)w1b + (size_t)kc * PANEL_B + u * 16 + j * 2)
            = __float2bfloat16(v);
    } else if (idx < W1B_ELEMS + W2B_ELEMS) {
        int j = idx - W1B_ELEMS;
        int ki = j & 31, t = j >> 5;
        int n = t & 127, kc = t >> 7;
        w2b[j] = __float2bfloat16(w2[(kc * 32 + ki) * 128 + n]);
    } else if (idx < W1B_ELEMS + W2B_ELEMS + W3B_ELEMS) {
        int j = idx - W1B_ELEMS - W2B_ELEMS;
        int ki = j & 31, t = j >> 5;
        int n = t & 15, kc = t >> 4;
        float v = (n < 10) ? w3[(kc * 32 + ki) * 10 + n] : 0.0f;  // zero-pad N 10->16
        w3b[j] = __float2bfloat16(v);
    }
}

// ---------------------------------------------------------------------------
// Kernel A: conv3x3 valid, fp32 exact, h0b[r][704] bf16 to global. (R7, proven)
template<int S>
__device__ __forceinline__ void conv_body(
        const float* __restrict__ xr, __hip_bfloat16* __restrict__ hp,
        float c00, float c01, float c02, float c10, float c11, float c12,
        float c20, float c21, float c22) {
    float4 v[3][4];
    #pragma unroll
    for (int d = 0; d < 3; d++) {
        const float4* p4 = (const float4*)(xr + d * 28);   // rows 112B -> 16B aligned
        #pragma unroll
        for (int q = 0; q < 4; q++) v[d][q] = p4[S * 3 + q];
    }
    #pragma unroll
    for (int d = 0; d < 3; d++)        // pins AFTER all loads issued (R8 lesson:
        #pragma unroll                 //  interleaved pins serialize issue)
        for (int q = 0; q < 4; q++) PIN4(v[d][q]);
    float rb[3][16];
    #pragma unroll
    for (int d = 0; d < 3; d++)
        #pragma unroll
        for (int q = 0; q < 4; q++) {
            rb[d][q*4+0] = v[d][q].x; rb[d][q*4+1] = v[d][q].y;
            rb[d][q*4+2] = v[d][q].z; rb[d][q*4+3] = v[d][q].w;
        }
    #pragma unroll
    for (int jj = 0; jj < 13; jj++) {
        float a = c00*rb[0][S+jj] + c01*rb[0][S+jj+1] + c02*rb[0][S+jj+2]
                + c10*rb[1][S+jj] + c11*rb[1][S+jj+1] + c12*rb[1][S+jj+2]
                + c20*rb[2][S+jj] + c21*rb[2][S+jj+1] + c22*rb[2][S+jj+2];
        hp[jj] = __float2bfloat16(a);
    }
}

__global__ __launch_bounds__(256, 4)
void conv_kernel(const float* __restrict__ x, const float* __restrict__ cw,
                 __hip_bfloat16* __restrict__ h0b) {
    const int tid  = threadIdx.x;
    const int half = tid >> 7;                         // wave-uniform (waves 0-1 / 2-3)
    const int u    = blockIdx.x * 128 + (tid & 127);   // (r,i) task id
    const int i    = u % 26;
    const int r    = u / 26;
    const float c00 = cw[0], c01 = cw[1], c02 = cw[2];
    const float c10 = cw[3], c11 = cw[4], c12 = cw[5];
    const float c20 = cw[6], c21 = cw[7], c22 = cw[8];
    const float* xr = x + (size_t)r * 784 + i * 28;
    __hip_bfloat16* hp = h0b + (size_t)r * 704 + i * 26 + half * 13;
    if (half == 0) conv_body<0>(xr, hp, c00, c01, c02, c10, c11, c12, c20, c21, c22);
    else           conv_body<1>(xr, hp, c00, c01, c02, c10, c11, c12, c20, c21, c22);
    // K-pad cols 676..703 -> zeros (one writer per image)
    if (half == 1 && i == 25) {
        uint* pz = (uint*)(h0b + (size_t)r * 704 + 676);   // byte 1352: 4B aligned
        #pragma unroll
        for (int q = 0; q < 14; q++) pz[q] = 0u;
    }
}

// ---------------------------------------------------------------------------
// Kernel B v3: m97-structure GEMM. GM=64 rows, 256 threads / 4 waves in a 2x2
// grid (wave -> mh=wave>>1: 32 rows, nh=wave&1: 128 cols; 16 MFMA/kc/wave).
// A (4KB/kc) and B (16KB/kc) double-buffered in LDS via global_load_lds w=16;
// ONE __syncthreads per kc (compiler emits the vmcnt drain -> guaranteed
// issue-one-iteration-ahead pipelining; no pins, no reg rings to defeat).
__global__ __launch_bounds__(256, 2)
void gemm_kernel(const __hip_bfloat16* __restrict__ h0b,
                 const __hip_bfloat16* __restrict__ w1b, const float* __restrict__ b1,
                 const __hip_bfloat16* __restrict__ w2b, const float* __restrict__ b2,
                 const __hip_bfloat16* __restrict__ w3b, const float* __restrict__ b3,
                 float* __restrict__ out) {
    // LDS: [astg 2x4096][bstg 2x16384][h1s 33792] = 74752B -> 2 blocks/CU.
    // h2s (17408B) overlays astg/bstg after GEMM1.
    __shared__ __align__(16) char smem[8192 + 32768 + GM * H1S * 2];
    char* astg = smem;
    char* bstg = smem + 8192;
    __hip_bfloat16* h1s = (__hip_bfloat16*)(smem + 40960);
    __hip_bfloat16* h2s = (__hip_bfloat16*)smem;

    const int tid  = threadIdx.x;
    const int r0   = blockIdx.x * GM;
    const int wave = tid >> 6;
    const int lane = tid & 63;
    const int l15  = lane & 15;
    const int g    = lane >> 4;
    const int mh   = wave >> 1;       // row-half (0..1)
    const int nh   = wave & 1;        // col-half (0..1)
    const int swg  = (g ^ (l15 & 3)) * 16;   // swizzled 16B slot within a 64B row

    // ---- GEMM1: h1 = relu(h0 @ w1 + b1), M=64 N=256 K=704 ----
    {
        f32x4 acc[2][8];
        #pragma unroll
        for (int mt = 0; mt < 2; mt++)
            #pragma unroll
            for (int nt = 0; nt < 8; nt++)
                acc[mt][nt] = (f32x4){0.f, 0.f, 0.f, 0.f};

        // staging source addresses: thread t stages LDS unit t (linear dest).
        // A: unit t holds (row=t>>2, g_eff=(t&3)^(row&3)) -> pre-swizzled source.
        const int srow = tid >> 2, sgx = tid & 3;
        const __hip_bfloat16* asrc = h0b + (size_t)(r0 + srow) * 704
                                         + (sgx ^ (srow & 3)) * 8;
        const char* bsrc = (const char*)w1b;   // already the swizzled LDS image

        // prologue: stage kc=0 into buf 0
        __builtin_amdgcn_global_load_lds((const uint32_t*)asrc,
            (uint32_t*)(astg + wave * 1024), 16, 0, 0);
        #pragma unroll
        for (int j2 = 0; j2 < 4; j2++)
            __builtin_amdgcn_global_load_lds(
                (const uint32_t*)(bsrc + j2 * 4096 + tid * 16),
                (uint32_t*)(bstg + j2 * 4096 + wave * 1024), 16, 0, 0);
        __syncthreads();   // vmcnt(0) drain: buf0 ready

        for (int kc = 0; kc < KC1; kc++) {
            const int cur = kc & 1;
            if (kc + 1 < KC1) {   // stage next tile into other buffer
                __builtin_amdgcn_global_load_lds(
                    (const uint32_t*)(asrc + (kc + 1) * 32),
                    (uint32_t*)(astg + (cur ^ 1) * 4096 + wave * 1024), 16, 0, 0);
                #pragma unroll
                for (int j2 = 0; j2 < 4; j2++)
                    __builtin_amdgcn_global_load_lds(
                        (const uint32_t*)(bsrc + (size_t)(kc + 1) * PANEL_B + j2 * 4096 + tid * 16),
                        (uint32_t*)(bstg + (cur ^ 1) * 16384 + j2 * 4096 + wave * 1024), 16, 0, 0);
            }
            bf16x8 av[2], bv[8];
            #pragma unroll
            for (int mt = 0; mt < 2; mt++)
                av[mt] = *(const bf16x8*)(astg + cur * 4096
                            + (mh * 32 + mt * 16 + l15) * 64 + swg);
            #pragma unroll
            for (int nt = 0; nt < 8; nt++)
                bv[nt] = *(const bf16x8*)(bstg + cur * 16384
                            + (nh * 128 + nt * 16 + l15) * 64 + swg);
            #pragma unroll
            for (int mt = 0; mt < 2; mt++)
                #pragma unroll
                for (int nt = 0; nt < 8; nt++)
                    acc[mt][nt] = __builtin_amdgcn_mfma_f32_16x16x32_bf16(
                        av[mt], bv[nt], acc[mt][nt], 0, 0, 0);
            __syncthreads();   // drains next-tile staging; buffers swap
        }
        #pragma unroll
        for (int nt = 0; nt < 8; nt++) {
            const int n = nh * 128 + nt * 16 + l15;
            const float bias = b1[n];
            #pragma unroll
            for (int mt = 0; mt < 2; mt++) {
                #pragma unroll
                for (int q = 0; q < 4; q++) {
                    const int row = mh * 32 + mt * 16 + g * 4 + q;  // C/D: col=l15, row=g*4+q
                    float v = acc[mt][nt][q] + bias;
                    h1s[row * H1S + n] = __float2bfloat16(fmaxf(v, 0.0f));
                }
            }
        }
    }
    __syncthreads();

    // ---- GEMM2: h2 = relu(h1 @ w2 + b2), M=64 N=128 K=256 ----
    // wave (mh,nh): 32 rows x 64 cols. A from LDS h1s; B from L2 (w2b hot,
    // 64KB), dist-2 ring, NO pins (R8 lesson).
    {
        f32x4 acc[2][4];
        #pragma unroll
        for (int mt = 0; mt < 2; mt++)
            #pragma unroll
            for (int nt = 0; nt < 4; nt++)
                acc[mt][nt] = (f32x4){0.f, 0.f, 0.f, 0.f};
        const int nb = nh * 64;
        bf16x8 bb2[3][4];
        #pragma unroll
        for (int p = 0; p < 2; p++)
            #pragma unroll
            for (int nt = 0; nt < 4; nt++)
                bb2[p][nt] = *(const bf16x8*)(w2b + ((p * 128 + nb + nt * 16 + l15) * 32 + g * 8));
        #pragma unroll
        for (int kc = 0; kc < KC2; kc++) {
            const int cur = kc % 3, nxt = (kc + 2) % 3;
            if (kc + 2 < KC2) {
                #pragma unroll
                for (int nt = 0; nt < 4; nt++)
                    bb2[nxt][nt] = *(const bf16x8*)(w2b + (((kc + 2) * 128 + nb + nt * 16 + l15) * 32 + g * 8));
            }
            bf16x8 ab[2];
            #pragma unroll
            for (int mt = 0; mt < 2; mt++)
                ab[mt] = *(const bf16x8*)(h1s + (mh * 32 + mt * 16 + l15) * H1S + kc * 32 + g * 8);
            #pragma unroll
            for (int mt = 0; mt < 2; mt++)
                #pragma unroll
                for (int nt = 0; nt < 4; nt++)
                    acc[mt][nt] = __builtin_amdgcn_mfma_f32_16x16x32_bf16(
                        ab[mt], bb2[cur][nt], acc[mt][nt], 0, 0, 0);
        }
        #pragma unroll
        for (int nt = 0; nt < 4; nt++) {
            const int n = nb + nt * 16 + l15;
            const float bias = b2[n];
            #pragma unroll
            for (int mt = 0; mt < 2; mt++) {
                #pragma unroll
                for (int q = 0; q < 4; q++) {
                    const int row = mh * 32 + mt * 16 + g * 4 + q;
                    float v = acc[mt][nt][q] + bias;
                    h2s[row * H2S + n] = __float2bfloat16(fmaxf(v, 0.0f));  // overlays stage bufs
                }
            }
        }
    }
    __syncthreads();

    // ---- GEMM3: out = h2 @ w3 + b3, M=64 N=16(10) K=128; 4 waves x 16 rows ----
    {
        f32x4 acc3 = (f32x4){0.f, 0.f, 0.f, 0.f};
        #pragma unroll
        for (int kc = 0; kc < KC3; kc++) {
            bf16x8 a = *(const bf16x8*)(h2s + (wave * 16 + l15) * H2S + kc * 32 + g * 8);
            bf16x8 b = *(const bf16x8*)(w3b + ((kc * 16 + l15) * 32 + g * 8));
            acc3 = __builtin_amdgcn_mfma_f32_16x16x32_bf16(a, b, acc3, 0, 0, 0);
        }
        if (l15 < 10) {
            const float bias = b3[l15];
            #pragma unroll
            for (int q = 0; q < 4; q++) {
                const int row = wave * 16 + g * 4 + q;
                out[(size_t)(r0 + row) * 10 + l15] = acc3[q] + bias;
            }
        }
    }
}

// ---------------------------------------------------------------------------
// Fallback: R3 fused kernel, adapted to the swizzled-image w1b layout.
__global__ __launch_bounds__(256, 2)
void fused_model(const float* __restrict__ x, const float* __restrict__ cw,
                 const __hip_bfloat16* __restrict__ w1b, const float* __restrict__ b1,
                 const __hip_bfloat16* __restrict__ w2b, const float* __restrict__ b2,
                 const __hip_bfloat16* __restrict__ w3b, const float* __restrict__ b3,
                 float* __restrict__ out) {
    __shared__ __align__(16) char smem[MR * H0S * 2 + MR * H1S * 2];
    __hip_bfloat16* h0s = (__hip_bfloat16*)smem;
    __hip_bfloat16* h1s = (__hip_bfloat16*)(smem + MR * H0S * 2);
    __hip_bfloat16* h2s = (__hip_bfloat16*)smem;
    const char* w1c = (const char*)w1b;

    const int tid = threadIdx.x;
    const int r0  = blockIdx.x * MR;

    const float c00 = cw[0], c01 = cw[1], c02 = cw[2];
    const float c10 = cw[3], c11 = cw[4], c12 = cw[5];
    const float c20 = cw[6], c21 = cw[7], c22 = cw[8];

    for (int t = tid; t < MR * 26; t += 256) {
        int r = t / 26;
        int i = t - r * 26;
        const float* xr = x + (size_t)(r0 + r) * 784 + i * 28;
        float4 v[21];
        #pragma unroll
        for (int di = 0; di < 3; di++) {
            const float4* p4 = (const float4*)(xr + di * 28);
            #pragma unroll
            for (int q = 0; q < 7; q++) v[di * 7 + q] = p4[q];
        }
        #pragma unroll
        for (int k = 0; k < 21; k++) PIN4(v[k]);
        float rb[3][28];
        #pragma unroll
        for (int di = 0; di < 3; di++) {
            #pragma unroll
            for (int q = 0; q < 7; q++) {
                rb[di][q*4+0] = v[di*7+q].x; rb[di][q*4+1] = v[di*7+q].y;
                rb[di][q*4+2] = v[di*7+q].z; rb[di][q*4+3] = v[di*7+q].w;
            }
        }
        __hip_bfloat162* hp = (__hip_bfloat162*)(h0s + r * H0S + i * 26);
        #pragma unroll
        for (int k = 0; k < 13; k++) {
            const int j0 = 2 * k, j1 = 2 * k + 1;
            float a0 = c00*rb[0][j0] + c01*rb[0][j0+1] + c02*rb[0][j0+2]
                     + c10*rb[1][j0] + c11*rb[1][j0+1] + c12*rb[1][j0+2]
                     + c20*rb[2][j0] + c21*rb[2][j0+1] + c22*rb[2][j0+2];
            float a1 = c00*rb[0][j1] + c01*rb[0][j1+1] + c02*rb[0][j1+2]
                     + c10*rb[1][j1] + c11*rb[1][j1+1] + c12*rb[1][j1+2]
                     + c20*rb[2][j1] + c21*rb[2][j1+1] + c22*rb[2][j1+2];
            __hip_bfloat162 pr;
            pr.x = __float2bfloat16(a0);
            pr.y = __float2bfloat16(a1);
            hp[k] = pr;
        }
    }
    for (int t = tid; t < MR * 18; t += 256) {
        int r = t / 18;
        int c = t - r * 18;
        ((uint*)(h0s + r * H0S + 676))[c] = 0u;
    }
    __syncthreads();

    const int wave = tid >> 6;
    const int lane = tid & 63;
    const int l15  = lane & 15;
    const int g    = lane >> 4;
    const int swg  = (g ^ (l15 & 3)) * 16;

    {   // GEMM1 (swizzled w1b image addressing)
        f32x4 acc[2][4];
        #pragma unroll
        for (int mt = 0; mt < 2; mt++)
            #pragma unroll
            for (int nt = 0; nt < 4; nt++)
                acc[mt][nt] = (f32x4){0.f, 0.f, 0.f, 0.f};
        const int nb = wave * 64;
        bf16x8 ab[3][2], bb[3][4];
        #pragma unroll
        for (int p = 0; p < 2; p++) {
            #pragma unroll
            for (int mt = 0; mt < 2; mt++)
                ab[p][mt] = *(const bf16x8*)(h0s + (mt * 16 + l15) * H0S + p * 32 + g * 8);
            #pragma unroll
            for (int nt = 0; nt < 4; nt++) {
                const int n = nb + nt * 16 + l15;
                bb[p][nt] = *(const bf16x8*)(w1c + (size_t)p * PANEL_B + n * 64 + swg);
            }
        }
        #pragma unroll
        for (int kc = 0; kc < KC1; kc++) {
            const int cur = kc % 3;
            const int nxt = (kc + 2) % 3;
            if (kc + 2 < KC1) {
                #pragma unroll
                for (int mt = 0; mt < 2; mt++)
                    ab[nxt][mt] = *(const bf16x8*)(h0s + (mt * 16 + l15) * H0S + (kc + 2) * 32 + g * 8);
                #pragma unroll
                for (int nt = 0; nt < 4; nt++) {
                    const int n = nb + nt * 16 + l15;
                    bb[nxt][nt] = *(const bf16x8*)(w1c + (size_t)(kc + 2) * PANEL_B + n * 64 + swg);
                }
            }
            #pragma unroll
            for (int mt = 0; mt < 2; mt++)
                #pragma unroll
                for (int nt = 0; nt < 4; nt++)
                    acc[mt][nt] = __builtin_amdgcn_mfma_f32_16x16x32_bf16(
                        ab[cur][mt], bb[cur][nt], acc[mt][nt], 0, 0, 0);
        }
        #pragma unroll
        for (int nt = 0; nt < 4; nt++) {
            const int n = nb + nt * 16 + l15;
            const float bias = b1[n];
            #pragma unroll
            for (int mt = 0; mt < 2; mt++) {
                #pragma unroll
                for (int q = 0; q < 4; q++) {
                    const int row = mt * 16 + g * 4 + q;
                    float v = acc[mt][nt][q] + bias;
                    h1s[row * H1S + n] = __float2bfloat16(fmaxf(v, 0.0f));
                }
            }
        }
    }
    __syncthreads();

    {   // GEMM2
        f32x4 acc[2][2];
        #pragma unroll
        for (int mt = 0; mt < 2; mt++)
            #pragma unroll
            for (int nt = 0; nt < 2; nt++)
                acc[mt][nt] = (f32x4){0.f, 0.f, 0.f, 0.f};
        const int nb = wave * 32;
        bf16x8 ab[3][2], bb[3][2];
        #pragma unroll
        for (int p = 0; p < 2; p++) {
            #pragma unroll
            for (int mt = 0; mt < 2; mt++)
                ab[p][mt] = *(const bf16x8*)(h1s + (mt * 16 + l15) * H1S + p * 32 + g * 8);
            #pragma unroll
            for (int nt = 0; nt < 2; nt++)
                bb[p][nt] = *(const bf16x8*)(w2b + ((p * 128 + nb + nt * 16 + l15) * 32 + g * 8));
        }
        #pragma unroll
        for (int kc = 0; kc < KC2; kc++) {
            const int cur = kc % 3;
            const int nxt = (kc + 2) % 3;
            if (kc + 2 < KC2) {
                #pragma unroll
                for (int mt = 0; mt < 2; mt++)
                    ab[nxt][mt] = *(const bf16x8*)(h1s + (mt * 16 + l15) * H1S + (kc + 2) * 32 + g * 8);
                #pragma unroll
                for (int nt = 0; nt < 2; nt++)
                    bb[nxt][nt] = *(const bf16x8*)(w2b + (((kc + 2) * 128 + nb + nt * 16 + l15) * 32 + g * 8));
            }
            #pragma unroll
            for (int mt = 0; mt < 2; mt++)
                #pragma unroll
                for (int nt = 0; nt < 2; nt++)
                    acc[mt][nt] = __builtin_amdgcn_mfma_f32_16x16x32_bf16(
                        ab[cur][mt], bb[cur][nt], acc[mt][nt], 0, 0, 0);
        }
        #pragma unroll
        for (int nt = 0; nt < 2; nt++) {
            const int n = nb + nt * 16 + l15;
            const float bias = b2[n];
            #pragma unroll
            for (int mt = 0; mt < 2; mt++) {
                #pragma unroll
                for (int q = 0; q < 4; q++) {
                    const int row = mt * 16 + g * 4 + q;
                    float v = acc[mt][nt][q] + bias;
                    h2s[row * H2S + n] = __float2bfloat16(fmaxf(v, 0.0f));
                }
            }
        }
    }
    __syncthreads();

    if (wave < 2) {  // GEMM3
        f32x4 acc3 = (f32x4){0.f, 0.f, 0.f, 0.f};
        #pragma unroll
        for (int kc = 0; kc < KC3; kc++) {
            bf16x8 a = *(const bf16x8*)(h2s + (wave * 16 + l15) * H2S + kc * 32 + g * 8);
            bf16x8 b = *(const bf16x8*)(w3b + ((kc * 16 + l15) * 32 + g * 8));
            acc3 = __builtin_amdgcn_mfma_f32_16x16x32_bf16(a, b, acc3, 0, 0, 0);
        }
        if (l15 < 10) {
            const float bias = b3[l15];
            #pragma unroll
            for (int q = 0; q < 4; q++) {
                const int row = wave * 16 + g * 4 + q;
                out[(size_t)(r0 + row) * 10 + l15] = acc3[q] + bias;
            }
        }
    }
}

extern "C" void kernel_launch(void* const* d_in, const int* in_sizes, int n_in,
                              void* d_out, int out_size, void* d_ws, size_t ws_size,
                              hipStream_t stream) {
    const float* x  = (const float*)d_in[0];
    const float* cw = (const float*)d_in[1];
    const float* w1 = (const float*)d_in[2];
    const float* b1 = (const float*)d_in[3];
    const float* w2 = (const float*)d_in[4];
    const float* b2 = (const float*)d_in[5];
    const float* w3 = (const float*)d_in[6];
    const float* b3 = (const float*)d_in[7];
    float* out = (float*)d_out;

    __hip_bfloat16* w1b = (__hip_bfloat16*)d_ws;
    __hip_bfloat16* w2b = (__hip_bfloat16*)((char*)d_ws + W1B_BYTES);
    __hip_bfloat16* w3b = w2b + W2B_ELEMS;

    const int pack_total = W1B_ELEMS + W2B_ELEMS + W3B_ELEMS;  // 215040
    pack_weights<<<(pack_total + 255) / 256, 256, 0, stream>>>(w1, w2, w3, w1b, w2b, w3b);

    const size_t need = (size_t)WS_WEIGHTS + H0B_BYTES;
    if (ws_size >= need) {
        __hip_bfloat16* h0b = (__hip_bfloat16*)((char*)d_ws + WS_WEIGHTS);
        conv_kernel<<<B_ROWS * 26 / 128, 256, 0, stream>>>(x, cw, h0b);
        gemm_kernel<<<B_ROWS / GM, 256, 0, stream>>>(h0b, w1b, b1, w2b, b2, w3b, b3, out);
    } else {
        fused_model<<<B_ROWS / MR, 256, 0, stream>>>(x, cw, w1b, b1, w2b, b2, w3b, b3, out);
    }
}

// Round 10
// 378.997 us; speedup vs baseline: 1.1782x; 1.0054x over previous
//
#include <hip/hip_runtime.h>
#include <hip/hip_bf16.h>
#include <stdint.h>

typedef __bf16 bf16x8 __attribute__((ext_vector_type(8)));
typedef float  f32x4  __attribute__((ext_vector_type(4)));
typedef unsigned short ushort8 __attribute__((ext_vector_type(8)));

#define PIN4(v) asm volatile("" :: "v"((v).x), "v"((v).y), "v"((v).z), "v"((v).w))

#define B_ROWS 65536
#define KC1 26           // K' = 832 = 26 lines x 32 (26 used + 6 pad per line)
#define KC1F 22          // fused-fallback K = 704
#define KC2 8            // 256/32
#define KC3 4            // 128/32
#define H1S 264          // h1 LDS stride (256+8 pad)
#define H2S 136          // h2 LDS stride (128+8 pad)
#define PANEL_B 16384    // one w1 K-panel: 256 n x 64B (swizzled LDS image)
#define W1SW_ELEMS (KC1*256*32)   // 212992
#define W1LIN_ELEMS (704*256)     // 180224
#define W2B_ELEMS (256*128)
#define W3B_ELEMS (128*16)
#define W1SW_BYTES (KC1*PANEL_B)                  // 425984
#define W1LIN_BYTES (W1LIN_ELEMS*2)               // 360448
#define WS_WEIGHTS (W1SW_BYTES + W1LIN_BYTES + W2B_ELEMS*2 + W3B_ELEMS*2)  // 856064
#define H0B_ELEMS ((size_t)B_ROWS*832)
#define H0B_BYTES (H0B_ELEMS*2)                   // 109MB
#define GM 64            // rows per gemm block

// fused-fallback geometry (R3)
#define MR 32
#define H0S 712

__device__ __forceinline__ unsigned short f2b(float f) {
    __hip_bfloat16 h = __float2bfloat16(f);
    return *reinterpret_cast<unsigned short*>(&h);
}

// ---------------------------------------------------------------------------
// Pack weights.
// w1sw: K'=832 swizzled LDS image. Element (kc, ki, n): value w1[(kc*26+ki)*256+n]
//   for ki<26 else 0; byte kc*16384 + (n*4 + ((ki>>3)^(n&3)))*16 + (ki&7)*2.
// w1lin: K=704 linear [kc][n][ki32] for the fused fallback.
// w2b/w3b: [kc][n][ki32] linear.
__global__ void pack_weights(const float* __restrict__ w1,
                             const float* __restrict__ w2,
                             const float* __restrict__ w3,
                             __hip_bfloat16* __restrict__ w1sw,
                             __hip_bfloat16* __restrict__ w1lin,
                             __hip_bfloat16* __restrict__ w2b,
                             __hip_bfloat16* __restrict__ w3b) {
    int idx = blockIdx.x * 256 + threadIdx.x;
    if (idx < W1SW_ELEMS) {
        int ki = idx & 31, t = idx >> 5;
        int n = t & 255, kc = t >> 8;             // kc 0..25
        float v = (ki < 26) ? w1[(kc * 26 + ki) * 256 + n] : 0.0f;
        size_t byte = (size_t)kc * PANEL_B
                    + (size_t)(n * 4 + ((ki >> 3) ^ (n & 3))) * 16 + (ki & 7) * 2;
        *(__hip_bfloat16*)((char*)w1sw + byte) = __float2bfloat16(v);
    } else if (idx < W1SW_ELEMS + W1LIN_ELEMS) {
        int j = idx - W1SW_ELEMS;
        int ki = j & 31, t = j >> 5;
        int n = t & 255, kc = t >> 8;
        int k = kc * 32 + ki;
        float v = (k < 676) ? w1[k * 256 + n] : 0.0f;
        w1lin[j] = __float2bfloat16(v);
    } else if (idx < W1SW_ELEMS + W1LIN_ELEMS + W2B_ELEMS) {
        int j = idx - W1SW_ELEMS - W1LIN_ELEMS;
        int ki = j & 31, t = j >> 5;
        int n = t & 127, kc = t >> 7;
        w2b[j] = __float2bfloat16(w2[(kc * 32 + ki) * 128 + n]);
    } else if (idx < W1SW_ELEMS + W1LIN_ELEMS + W2B_ELEMS + W3B_ELEMS) {
        int j = idx - W1SW_ELEMS - W1LIN_ELEMS - W2B_ELEMS;
        int ki = j & 31, t = j >> 5;
        int n = t & 15, kc = t >> 4;
        float v = (n < 10) ? w3[(kc * 32 + ki) * 10 + n] : 0.0f;
        w3b[j] = __float2bfloat16(v);
    }
}

// ---------------------------------------------------------------------------
// Kernel A v3: conv3x3 valid, fp32 exact. Task = (image r, out-row i): 21
// float4 loads issued then pinned (R3/R8 lesson: pins AFTER all loads),
// 26 outputs + 6 zero-pads packed into one 64B line -> 4 aligned 16B stores.
// h0b layout [r][i*32 + j]: K'=832, pads zero (w1sw has matching zeros).
__global__ __launch_bounds__(256, 2)
void conv_kernel(const float* __restrict__ x, const float* __restrict__ cw,
                 __hip_bfloat16* __restrict__ h0b) {
    const int u = blockIdx.x * 256 + threadIdx.x;   // 65536*26 tasks
    const int r = u / 26;
    const int i = u - r * 26;
    const float c00 = cw[0], c01 = cw[1], c02 = cw[2];
    const float c10 = cw[3], c11 = cw[4], c12 = cw[5];
    const float c20 = cw[6], c21 = cw[7], c22 = cw[8];
    const float* xr = x + (size_t)r * 784 + i * 28;

    float4 v[3][7];
    #pragma unroll
    for (int d = 0; d < 3; d++) {
        const float4* p4 = (const float4*)(xr + d * 28);   // 112B rows -> 16B aligned
        #pragma unroll
        for (int q = 0; q < 7; q++) v[d][q] = p4[q];
    }
    #pragma unroll
    for (int d = 0; d < 3; d++)
        #pragma unroll
        for (int q = 0; q < 7; q++) PIN4(v[d][q]);

    float rb[3][28];
    #pragma unroll
    for (int d = 0; d < 3; d++)
        #pragma unroll
        for (int q = 0; q < 7; q++) {
            rb[d][q*4+0] = v[d][q].x; rb[d][q*4+1] = v[d][q].y;
            rb[d][q*4+2] = v[d][q].z; rb[d][q*4+3] = v[d][q].w;
        }
    ushort8 o[4];
    #pragma unroll
    for (int jj = 0; jj < 26; jj++) {
        float a = c00*rb[0][jj] + c01*rb[0][jj+1] + c02*rb[0][jj+2]
                + c10*rb[1][jj] + c11*rb[1][jj+1] + c12*rb[1][jj+2]
                + c20*rb[2][jj] + c21*rb[2][jj+1] + c22*rb[2][jj+2];
        o[jj >> 3][jj & 7] = f2b(a);
    }
    #pragma unroll
    for (int jj = 26; jj < 32; jj++) o[3][jj & 7] = 0;

    unsigned short* hp = (unsigned short*)(h0b + (size_t)r * 832 + i * 32);  // 64B-aligned
    #pragma unroll
    for (int q = 0; q < 4; q++) *(ushort8*)(hp + q * 8) = o[q];
}

// ---------------------------------------------------------------------------
// Kernel B v4: m97-structure GEMM, 512 threads / 8 waves (2 mh x 4 nq grid).
// A (4KB/kc) + B (16KB/kc) double-buffered via global_load_lds w=16, one
// __syncthreads per kc. LDS 74752B -> 2 blocks/CU = 16 waves/CU: the kc loop
// is stage-latency-bound (16 MFMA ~80cy vs ~400cy stage), so TLP covers it.
__global__ __launch_bounds__(512, 4)
void gemm_kernel(const __hip_bfloat16* __restrict__ h0b,
                 const __hip_bfloat16* __restrict__ w1sw, const float* __restrict__ b1,
                 const __hip_bfloat16* __restrict__ w2b, const float* __restrict__ b2,
                 const __hip_bfloat16* __restrict__ w3b, const float* __restrict__ b3,
                 float* __restrict__ out) {
    // LDS: [astg 2x4096][bstg 2x16384][h1s 33792] = 74752B; h2s overlays astg/bstg.
    __shared__ __align__(16) char smem[8192 + 32768 + GM * H1S * 2];
    char* astg = smem;
    char* bstg = smem + 8192;
    __hip_bfloat16* h1s = (__hip_bfloat16*)(smem + 40960);
    __hip_bfloat16* h2s = (__hip_bfloat16*)smem;

    const int tid  = threadIdx.x;
    const int r0   = blockIdx.x * GM;
    const int wave = tid >> 6;        // 0..7
    const int lane = tid & 63;
    const int l15  = lane & 15;
    const int g    = lane >> 4;
    const int mh   = wave >> 2;       // row-half (0..1): 32 rows
    const int nq   = wave & 3;        // col-quarter (0..3): 64 cols
    const int swg  = (g ^ (l15 & 3)) * 16;   // swizzled 16B slot in a 64B row

    // ---- GEMM1: h1 = relu(h0 @ w1 + b1), M=64 N=256 K'=832 ----
    {
        f32x4 acc[2][4];
        #pragma unroll
        for (int mt = 0; mt < 2; mt++)
            #pragma unroll
            for (int nt = 0; nt < 4; nt++)
                acc[mt][nt] = (f32x4){0.f, 0.f, 0.f, 0.f};

        // staging sources (linear LDS dests; A source pre-swizzled, rule #21)
        const int srow = tid >> 2, sgx = tid & 3;          // threads 0..255
        const __hip_bfloat16* asrc = h0b + (size_t)(r0 + srow) * 832
                                         + (sgx ^ (srow & 3)) * 8;
        const char* bsrc = (const char*)w1sw;

        // prologue: stage kc=0 into buf 0
        if (tid < 256)
            __builtin_amdgcn_global_load_lds((const uint32_t*)asrc,
                (uint32_t*)(astg + wave * 1024), 16, 0, 0);
        #pragma unroll
        for (int j2 = 0; j2 < 2; j2++)
            __builtin_amdgcn_global_load_lds(
                (const uint32_t*)(bsrc + j2 * 8192 + tid * 16),
                (uint32_t*)(bstg + j2 * 8192 + wave * 1024), 16, 0, 0);
        __syncthreads();   // vmcnt drain: buf0 ready

        for (int kc = 0; kc < KC1; kc++) {
            const int cur = kc & 1;
            if (kc + 1 < KC1) {   // stage next tile into other buffer
                if (tid < 256)
                    __builtin_amdgcn_global_load_lds(
                        (const uint32_t*)(asrc + (kc + 1) * 32),
                        (uint32_t*)(astg + (cur ^ 1) * 4096 + wave * 1024), 16, 0, 0);
                #pragma unroll
                for (int j2 = 0; j2 < 2; j2++)
                    __builtin_amdgcn_global_load_lds(
                        (const uint32_t*)(bsrc + (size_t)(kc + 1) * PANEL_B + j2 * 8192 + tid * 16),
                        (uint32_t*)(bstg + (cur ^ 1) * 16384 + j2 * 8192 + wave * 1024), 16, 0, 0);
            }
            bf16x8 av[2], bv[4];
            #pragma unroll
            for (int mt = 0; mt < 2; mt++)
                av[mt] = *(const bf16x8*)(astg + cur * 4096
                            + (mh * 32 + mt * 16 + l15) * 64 + swg);
            #pragma unroll
            for (int nt = 0; nt < 4; nt++)
                bv[nt] = *(const bf16x8*)(bstg + cur * 16384
                            + (nq * 64 + nt * 16 + l15) * 64 + swg);
            #pragma unroll
            for (int mt = 0; mt < 2; mt++)
                #pragma unroll
                for (int nt = 0; nt < 4; nt++)
                    acc[mt][nt] = __builtin_amdgcn_mfma_f32_16x16x32_bf16(
                        av[mt], bv[nt], acc[mt][nt], 0, 0, 0);
            __syncthreads();   // drains next-tile staging; buffers swap
        }
        #pragma unroll
        for (int nt = 0; nt < 4; nt++) {
            const int n = nq * 64 + nt * 16 + l15;
            const float bias = b1[n];
            #pragma unroll
            for (int mt = 0; mt < 2; mt++) {
                #pragma unroll
                for (int q = 0; q < 4; q++) {
                    const int row = mh * 32 + mt * 16 + g * 4 + q;  // C/D: col=l15, row=g*4+q
                    float v = acc[mt][nt][q] + bias;
                    h1s[row * H1S + n] = __float2bfloat16(fmaxf(v, 0.0f));
                }
            }
        }
    }
    __syncthreads();

    // ---- GEMM2: h2 = relu(h1 @ w2 + b2), M=64 N=128 K=256 ----
    // wave (mh, nq): 32 rows x 32 cols. B from L2 (w2b hot), dist-2 ring, no pins.
    {
        f32x4 acc[2][2];
        #pragma unroll
        for (int mt = 0; mt < 2; mt++)
            #pragma unroll
            for (int nt = 0; nt < 2; nt++)
                acc[mt][nt] = (f32x4){0.f, 0.f, 0.f, 0.f};
        const int nb = nq * 32;
        bf16x8 bb2[3][2];
        #pragma unroll
        for (int p = 0; p < 2; p++)
            #pragma unroll
            for (int nt = 0; nt < 2; nt++)
                bb2[p][nt] = *(const bf16x8*)(w2b + ((p * 128 + nb + nt * 16 + l15) * 32 + g * 8));
        #pragma unroll
        for (int kc = 0; kc < KC2; kc++) {
            const int cur = kc % 3, nxt = (kc + 2) % 3;
            if (kc + 2 < KC2) {
                #pragma unroll
                for (int nt = 0; nt < 2; nt++)
                    bb2[nxt][nt] = *(const bf16x8*)(w2b + (((kc + 2) * 128 + nb + nt * 16 + l15) * 32 + g * 8));
            }
            bf16x8 ab[2];
            #pragma unroll
            for (int mt = 0; mt < 2; mt++)
                ab[mt] = *(const bf16x8*)(h1s + (mh * 32 + mt * 16 + l15) * H1S + kc * 32 + g * 8);
            #pragma unroll
            for (int mt = 0; mt < 2; mt++)
                #pragma unroll
                for (int nt = 0; nt < 2; nt++)
                    acc[mt][nt] = __builtin_amdgcn_mfma_f32_16x16x32_bf16(
                        ab[mt], bb2[cur][nt], acc[mt][nt], 0, 0, 0);
        }
        #pragma unroll
        for (int nt = 0; nt < 2; nt++) {
            const int n = nb + nt * 16 + l15;
            const float bias = b2[n];
            #pragma unroll
            for (int mt = 0; mt < 2; mt++) {
                #pragma unroll
                for (int q = 0; q < 4; q++) {
                    const int row = mh * 32 + mt * 16 + g * 4 + q;
                    float v = acc[mt][nt][q] + bias;
                    h2s[row * H2S + n] = __float2bfloat16(fmaxf(v, 0.0f));  // overlays stage bufs
                }
            }
        }
    }
    __syncthreads();

    // ---- GEMM3: out = h2 @ w3 + b3, M=64 N=16(10) K=128; waves 0..3 x 16 rows ----
    if (wave < 4) {
        f32x4 acc3 = (f32x4){0.f, 0.f, 0.f, 0.f};
        #pragma unroll
        for (int kc = 0; kc < KC3; kc++) {
            bf16x8 a = *(const bf16x8*)(h2s + (wave * 16 + l15) * H2S + kc * 32 + g * 8);
            bf16x8 b = *(const bf16x8*)(w3b + ((kc * 16 + l15) * 32 + g * 8));
            acc3 = __builtin_amdgcn_mfma_f32_16x16x32_bf16(a, b, acc3, 0, 0, 0);
        }
        if (l15 < 10) {
            const float bias = b3[l15];
            #pragma unroll
            for (int q = 0; q < 4; q++) {
                const int row = wave * 16 + g * 4 + q;
                out[(size_t)(r0 + row) * 10 + l15] = acc3[q] + bias;
            }
        }
    }
}

// ---------------------------------------------------------------------------
// Fallback: R3 fused kernel (proven), linear w1lin layout. Never used when
// workspace is large enough; kept for safety.
__global__ __launch_bounds__(256, 2)
void fused_model(const float* __restrict__ x, const float* __restrict__ cw,
                 const __hip_bfloat16* __restrict__ w1b, const float* __restrict__ b1,
                 const __hip_bfloat16* __restrict__ w2b, const float* __restrict__ b2,
                 const __hip_bfloat16* __restrict__ w3b, const float* __restrict__ b3,
                 float* __restrict__ out) {
    __shared__ __align__(16) char smem[MR * H0S * 2 + MR * H1S * 2];
    __hip_bfloat16* h0s = (__hip_bfloat16*)smem;
    __hip_bfloat16* h1s = (__hip_bfloat16*)(smem + MR * H0S * 2);
    __hip_bfloat16* h2s = (__hip_bfloat16*)smem;

    const int tid = threadIdx.x;
    const int r0  = blockIdx.x * MR;

    const float c00 = cw[0], c01 = cw[1], c02 = cw[2];
    const float c10 = cw[3], c11 = cw[4], c12 = cw[5];
    const float c20 = cw[6], c21 = cw[7], c22 = cw[8];

    for (int t = tid; t < MR * 26; t += 256) {
        int r = t / 26;
        int i = t - r * 26;
        const float* xr = x + (size_t)(r0 + r) * 784 + i * 28;
        float4 v[21];
        #pragma unroll
        for (int di = 0; di < 3; di++) {
            const float4* p4 = (const float4*)(xr + di * 28);
            #pragma unroll
            for (int q = 0; q < 7; q++) v[di * 7 + q] = p4[q];
        }
        #pragma unroll
        for (int k = 0; k < 21; k++) PIN4(v[k]);
        float rb[3][28];
        #pragma unroll
        for (int di = 0; di < 3; di++) {
            #pragma unroll
            for (int q = 0; q < 7; q++) {
                rb[di][q*4+0] = v[di*7+q].x; rb[di][q*4+1] = v[di*7+q].y;
                rb[di][q*4+2] = v[di*7+q].z; rb[di][q*4+3] = v[di*7+q].w;
            }
        }
        __hip_bfloat162* hp = (__hip_bfloat162*)(h0s + r * H0S + i * 26);
        #pragma unroll
        for (int k = 0; k < 13; k++) {
            const int j0 = 2 * k, j1 = 2 * k + 1;
            float a0 = c00*rb[0][j0] + c01*rb[0][j0+1] + c02*rb[0][j0+2]
                     + c10*rb[1][j0] + c11*rb[1][j0+1] + c12*rb[1][j0+2]
                     + c20*rb[2][j0] + c21*rb[2][j0+1] + c22*rb[2][j0+2];
            float a1 = c00*rb[0][j1] + c01*rb[0][j1+1] + c02*rb[0][j1+2]
                     + c10*rb[1][j1] + c11*rb[1][j1+1] + c12*rb[1][j1+2]
                     + c20*rb[2][j1] + c21*rb[2][j1+1] + c22*rb[2][j1+2];
            __hip_bfloat162 pr;
            pr.x = __float2bfloat16(a0);
            pr.y = __float2bfloat16(a1);
            hp[k] = pr;
        }
    }
    for (int t = tid; t < MR * 18; t += 256) {
        int r = t / 18;
        int c = t - r * 18;
        ((uint*)(h0s + r * H0S + 676))[c] = 0u;
    }
    __syncthreads();

    const int wave = tid >> 6;
    const int lane = tid & 63;
    const int l15  = lane & 15;
    const int g    = lane >> 4;

    {   // GEMM1 (linear w1lin)
        f32x4 acc[2][4];
        #pragma unroll
        for (int mt = 0; mt < 2; mt++)
            #pragma unroll
            for (int nt = 0; nt < 4; nt++)
                acc[mt][nt] = (f32x4){0.f, 0.f, 0.f, 0.f};
        const int nb = wave * 64;
        bf16x8 ab[3][2], bb[3][4];
        #pragma unroll
        for (int p = 0; p < 2; p++) {
            #pragma unroll
            for (int mt = 0; mt < 2; mt++)
                ab[p][mt] = *(const bf16x8*)(h0s + (mt * 16 + l15) * H0S + p * 32 + g * 8);
            #pragma unroll
            for (int nt = 0; nt < 4; nt++)
                bb[p][nt] = *(const bf16x8*)(w1b + ((p * 256 + nb + nt * 16 + l15) * 32 + g * 8));
        }
        #pragma unroll
        for (int kc = 0; kc < KC1F; kc++) {
            const int cur = kc % 3;
            const int nxt = (kc + 2) % 3;
            if (kc + 2 < KC1F) {
                #pragma unroll
                for (int mt = 0; mt < 2; mt++)
                    ab[nxt][mt] = *(const bf16x8*)(h0s + (mt * 16 + l15) * H0S + (kc + 2) * 32 + g * 8);
                #pragma unroll
                for (int nt = 0; nt < 4; nt++)
                    bb[nxt][nt] = *(const bf16x8*)(w1b + (((kc + 2) * 256 + nb + nt * 16 + l15) * 32 + g * 8));
            }
            #pragma unroll
            for (int mt = 0; mt < 2; mt++)
                #pragma unroll
                for (int nt = 0; nt < 4; nt++)
                    acc[mt][nt] = __builtin_amdgcn_mfma_f32_16x16x32_bf16(
                        ab[cur][mt], bb[cur][nt], acc[mt][nt], 0, 0, 0);
        }
        #pragma unroll
        for (int nt = 0; nt < 4; nt++) {
            const int n = nb + nt * 16 + l15;
            const float bias = b1[n];
            #pragma unroll
            for (int mt = 0; mt < 2; mt++) {
                #pragma unroll
                for (int q = 0; q < 4; q++) {
                    const int row = mt * 16 + g * 4 + q;
                    float v = acc[mt][nt][q] + bias;
                    h1s[row * H1S + n] = __float2bfloat16(fmaxf(v, 0.0f));
                }
            }
        }
    }
    __syncthreads();

    {   // GEMM2
        f32x4 acc[2][2];
        #pragma unroll
        for (int mt = 0; mt < 2; mt++)
            #pragma unroll
            for (int nt = 0; nt < 2; nt++)
                acc[mt][nt] = (f32x4){0.f, 0.f, 0.f, 0.f};
        const int nb = wave * 32;
        bf16x8 ab[3][2], bb[3][2];
        #pragma unroll
        for (int p = 0; p < 2; p++) {
            #pragma unroll
            for (int mt = 0; mt < 2; mt++)
                ab[p][mt] = *(const bf16x8*)(h1s + (mt * 16 + l15) * H1S + p * 32 + g * 8);
            #pragma unroll
            for (int nt = 0; nt < 2; nt++)
                bb[p][nt] = *(const bf16x8*)(w2b + ((p * 128 + nb + nt * 16 + l15) * 32 + g * 8));
        }
        #pragma unroll
        for (int kc = 0; kc < KC2; kc++) {
            const int cur = kc % 3;
            const int nxt = (kc + 2) % 3;
            if (kc + 2 < KC2) {
                #pragma unroll
                for (int mt = 0; mt < 2; mt++)
                    ab[nxt][mt] = *(const bf16x8*)(h1s + (mt * 16 + l15) * H1S + (kc + 2) * 32 + g * 8);
                #pragma unroll
                for (int nt = 0; nt < 2; nt++)
                    bb[nxt][nt] = *(const bf16x8*)(w2b + (((kc + 2) * 128 + nb + nt * 16 + l15) * 32 + g * 8));
            }
            #pragma unroll
            for (int mt = 0; mt < 2; mt++)
                #pragma unroll
                for (int nt = 0; nt < 2; nt++)
                    acc[mt][nt] = __builtin_amdgcn_mfma_f32_16x16x32_bf16(
                        ab[cur][mt], bb[cur][nt], acc[mt][nt], 0, 0, 0);
        }
        #pragma unroll
        for (int nt = 0; nt < 2; nt++) {
            const int n = nb + nt * 16 + l15;
            const float bias = b2[n];
            #pragma unroll
            for (int mt = 0; mt < 2; mt++) {
                #pragma unroll
                for (int q = 0; q < 4; q++) {
                    const int row = mt * 16 + g * 4 + q;
                    float v = acc[mt][nt][q] + bias;
                    h2s[row * H2S + n] = __float2bfloat16(fmaxf(v, 0.0f));
                }
            }
        }
    }
    __syncthreads();

    if (wave < 2) {  // GEMM3
        f32x4 acc3 = (f32x4){0.f, 0.f, 0.f, 0.f};
        #pragma unroll
        for (int kc = 0; kc < KC3; kc++) {
            bf16x8 a = *(const bf16x8*)(h2s + (wave * 16 + l15) * H2S + kc * 32 + g * 8);
            bf16x8 b = *(const bf16x8*)(w3b + ((kc * 16 + l15) * 32 + g * 8));
            acc3 = __builtin_amdgcn_mfma_f32_16x16x32_bf16(a, b, acc3, 0, 0, 0);
        }
        if (l15 < 10) {
            const float bias = b3[l15];
            #pragma unroll
            for (int q = 0; q < 4; q++) {
                const int row = wave * 16 + g * 4 + q;
                out[(size_t)(r0 + row) * 10 + l15] = acc3[q] + bias;
            }
        }
    }
}

extern "C" void kernel_launch(void* const* d_in, const int* in_sizes, int n_in,
                              void* d_out, int out_size, void* d_ws, size_t ws_size,
                              hipStream_t stream) {
    const float* x  = (const float*)d_in[0];
    const float* cw = (const float*)d_in[1];
    const float* w1 = (const float*)d_in[2];
    const float* b1 = (const float*)d_in[3];
    const float* w2 = (const float*)d_in[4];
    const float* b2 = (const float*)d_in[5];
    const float* w3 = (const float*)d_in[6];
    const float* b3 = (const float*)d_in[7];
    float* out = (float*)d_out;

    __hip_bfloat16* w1sw  = (__hip_bfloat16*)d_ws;
    __hip_bfloat16* w1lin = (__hip_bfloat16*)((char*)d_ws + W1SW_BYTES);
    __hip_bfloat16* w2b   = (__hip_bfloat16*)((char*)d_ws + W1SW_BYTES + W1LIN_BYTES);
    __hip_bfloat16* w3b   = w2b + W2B_ELEMS;

    const int pack_total = W1SW_ELEMS + W1LIN_ELEMS + W2B_ELEMS + W3B_ELEMS;  // 428032
    pack_weights<<<(pack_total + 255) / 256, 256, 0, stream>>>(
        w1, w2, w3, w1sw, w1lin, w2b, w3b);

    const size_t need = (size_t)WS_WEIGHTS + H0B_BYTES;   // ~110MB
    if (ws_size >= need) {
        __hip_bfloat16* h0b = (__hip_bfloat16*)((char*)d_ws + WS_WEIGHTS);
        conv_kernel<<<B_ROWS * 26 / 256, 256, 0, stream>>>(x, cw, h0b);
        gemm_kernel<<<B_ROWS / GM, 512, 0, stream>>>(h0b, w1sw, b1, w2b, b2, w3b, b3, out);
    } else {
        fused_model<<<B_ROWS / MR, 256, 0, stream>>>(x, cw, w1lin, b1, w2b, b2, w3b, b3, out);
    }
}

// Round 11
// 375.410 us; speedup vs baseline: 1.1894x; 1.0096x over previous
//
#include <hip/hip_runtime.h>
#include <hip/hip_bf16.h>
#include <stdint.h>

typedef __bf16 bf16x8 __attribute__((ext_vector_type(8)));
typedef float  f32x4  __attribute__((ext_vector_type(4)));
typedef unsigned short ushort8 __attribute__((ext_vector_type(8)));

#define PIN4(v) asm volatile("" :: "v"((v).x), "v"((v).y), "v"((v).z), "v"((v).w))

#define B_ROWS 65536
#define KC1 26           // K' = 832 = 26 lines x 32 (26 used + 6 pad per line)
#define KC1F 22          // fused-fallback K = 704
#define KC2 8            // 256/32
#define KC3 4            // 128/32
#define H1S 264          // h1 LDS stride (256+8 pad)
#define H2S 136          // h2 LDS stride (128+8 pad)
#define PANEL_B 16384    // one w1 K-panel: 256 n x 64B (swizzled LDS image)
#define W1SW_ELEMS (KC1*256*32)   // 212992
#define W1LIN_ELEMS (704*256)     // 180224
#define W2B_ELEMS (256*128)
#define W3B_ELEMS (128*16)
#define W1SW_BYTES (KC1*PANEL_B)                  // 425984
#define W1LIN_BYTES (W1LIN_ELEMS*2)               // 360448
#define WS_WEIGHTS (W1SW_BYTES + W1LIN_BYTES + W2B_ELEMS*2 + W3B_ELEMS*2)  // 856064
#define H0B_ELEMS ((size_t)B_ROWS*832)
#define H0B_BYTES (H0B_ELEMS*2)                   // 109MB
#define GM 64            // rows per gemm block

// fused-fallback geometry (R3)
#define MR 32
#define H0S 712

__device__ __forceinline__ unsigned short f2b(float f) {
    __hip_bfloat16 h = __float2bfloat16(f);
    return *reinterpret_cast<unsigned short*>(&h);
}

// constant-index component select from a float4[7] row (folds to a register
// after full unroll; replaces the rb[3][28] copy that doubled live VGPRs)
__device__ __forceinline__ float getv(const float4* vr, int j) {
    const float4 q = vr[j >> 2];
    const int m = j & 3;
    return m == 0 ? q.x : (m == 1 ? q.y : (m == 2 ? q.z : q.w));
}

// ---------------------------------------------------------------------------
// Pack weights.
// w1sw: K'=832 swizzled LDS image. Element (kc, ki, n): value w1[(kc*26+ki)*256+n]
//   for ki<26 else 0; byte kc*16384 + (n*4 + ((ki>>3)^(n&3)))*16 + (ki&7)*2.
// w1lin: K=704 linear [kc][n][ki32] for the fused fallback.
// w2b/w3b: [kc][n][ki32] linear.
__global__ void pack_weights(const float* __restrict__ w1,
                             const float* __restrict__ w2,
                             const float* __restrict__ w3,
                             __hip_bfloat16* __restrict__ w1sw,
                             __hip_bfloat16* __restrict__ w1lin,
                             __hip_bfloat16* __restrict__ w2b,
                             __hip_bfloat16* __restrict__ w3b) {
    int idx = blockIdx.x * 256 + threadIdx.x;
    if (idx < W1SW_ELEMS) {
        int ki = idx & 31, t = idx >> 5;
        int n = t & 255, kc = t >> 8;             // kc 0..25
        float v = (ki < 26) ? w1[(kc * 26 + ki) * 256 + n] : 0.0f;
        size_t byte = (size_t)kc * PANEL_B
                    + (size_t)(n * 4 + ((ki >> 3) ^ (n & 3))) * 16 + (ki & 7) * 2;
        *(__hip_bfloat16*)((char*)w1sw + byte) = __float2bfloat16(v);
    } else if (idx < W1SW_ELEMS + W1LIN_ELEMS) {
        int j = idx - W1SW_ELEMS;
        int ki = j & 31, t = j >> 5;
        int n = t & 255, kc = t >> 8;
        int k = kc * 32 + ki;
        float v = (k < 676) ? w1[k * 256 + n] : 0.0f;
        w1lin[j] = __float2bfloat16(v);
    } else if (idx < W1SW_ELEMS + W1LIN_ELEMS + W2B_ELEMS) {
        int j = idx - W1SW_ELEMS - W1LIN_ELEMS;
        int ki = j & 31, t = j >> 5;
        int n = t & 127, kc = t >> 7;
        w2b[j] = __float2bfloat16(w2[(kc * 32 + ki) * 128 + n]);
    } else if (idx < W1SW_ELEMS + W1LIN_ELEMS + W2B_ELEMS + W3B_ELEMS) {
        int j = idx - W1SW_ELEMS - W1LIN_ELEMS - W2B_ELEMS;
        int ki = j & 31, t = j >> 5;
        int n = t & 15, kc = t >> 4;
        float v = (n < 10) ? w3[(kc * 32 + ki) * 10 + n] : 0.0f;
        w3b[j] = __float2bfloat16(v);
    }
}

// ---------------------------------------------------------------------------
// Kernel A v5: conv3x3 valid, fp32 exact. Task = (image r, out-row i):
// 21 float4 issued then pinned (pins AFTER all loads — R8 lesson), outputs
// read the pinned regs DIRECTLY (no rb copy -> ~115 live VGPR, fits the 128
// cap) -> __launch_bounds__(256,4): 16 waves/CU x 21 loads = 336 outstanding
// per CU -> HBM-BW-bound (~50-60us), not latency-bound (R7-R10: 192 -> 108us).
// Output: one 64B line [26 outputs + 6 zero-pads] -> 4 aligned 16B stores,
// consecutive tasks cover h0b contiguously.
__global__ __launch_bounds__(256, 4)
void conv_kernel(const float* __restrict__ x, const float* __restrict__ cw,
                 __hip_bfloat16* __restrict__ h0b) {
    const int u = blockIdx.x * 256 + threadIdx.x;   // 65536*26 tasks
    const int r = u / 26;
    const int i = u - r * 26;
    const float c00 = cw[0], c01 = cw[1], c02 = cw[2];   // uniform -> SGPR
    const float c10 = cw[3], c11 = cw[4], c12 = cw[5];
    const float c20 = cw[6], c21 = cw[7], c22 = cw[8];
    const float* xr = x + (size_t)r * 784 + i * 28;

    float4 v[3][7];
    #pragma unroll
    for (int d = 0; d < 3; d++) {
        const float4* p4 = (const float4*)(xr + d * 28);   // 112B rows -> 16B aligned
        #pragma unroll
        for (int q = 0; q < 7; q++) v[d][q] = p4[q];
    }
    #pragma unroll
    for (int d = 0; d < 3; d++)
        #pragma unroll
        for (int q = 0; q < 7; q++) PIN4(v[d][q]);

    ushort8 o[4];
    #pragma unroll
    for (int jj = 0; jj < 26; jj++) {
        float a = c00 * getv(v[0], jj) + c01 * getv(v[0], jj + 1) + c02 * getv(v[0], jj + 2)
                + c10 * getv(v[1], jj) + c11 * getv(v[1], jj + 1) + c12 * getv(v[1], jj + 2)
                + c20 * getv(v[2], jj) + c21 * getv(v[2], jj + 1) + c22 * getv(v[2], jj + 2);
        o[jj >> 3][jj & 7] = f2b(a);
    }
    #pragma unroll
    for (int jj = 26; jj < 32; jj++) o[3][jj & 7] = 0;

    unsigned short* hp = (unsigned short*)(h0b + (size_t)r * 832 + i * 32);  // 64B-aligned
    #pragma unroll
    for (int q = 0; q < 4; q++) *(ushort8*)(hp + q * 8) = o[q];
}

// ---------------------------------------------------------------------------
// Kernel B v4 (unchanged from R10): m97-structure GEMM, 512 threads / 8 waves
// (2 mh x 4 nq). A (4KB/kc) + B (16KB/kc) double-buffered via global_load_lds
// w=16, one __syncthreads per kc. LDS 74752B -> 2 blocks/CU = 16 waves/CU.
__global__ __launch_bounds__(512, 4)
void gemm_kernel(const __hip_bfloat16* __restrict__ h0b,
                 const __hip_bfloat16* __restrict__ w1sw, const float* __restrict__ b1,
                 const __hip_bfloat16* __restrict__ w2b, const float* __restrict__ b2,
                 const __hip_bfloat16* __restrict__ w3b, const float* __restrict__ b3,
                 float* __restrict__ out) {
    __shared__ __align__(16) char smem[8192 + 32768 + GM * H1S * 2];
    char* astg = smem;
    char* bstg = smem + 8192;
    __hip_bfloat16* h1s = (__hip_bfloat16*)(smem + 40960);
    __hip_bfloat16* h2s = (__hip_bfloat16*)smem;

    const int tid  = threadIdx.x;
    const int r0   = blockIdx.x * GM;
    const int wave = tid >> 6;        // 0..7
    const int lane = tid & 63;
    const int l15  = lane & 15;
    const int g    = lane >> 4;
    const int mh   = wave >> 2;       // row-half (0..1): 32 rows
    const int nq   = wave & 3;        // col-quarter (0..3): 64 cols
    const int swg  = (g ^ (l15 & 3)) * 16;   // swizzled 16B slot in a 64B row

    // ---- GEMM1: h1 = relu(h0 @ w1 + b1), M=64 N=256 K'=832 ----
    {
        f32x4 acc[2][4];
        #pragma unroll
        for (int mt = 0; mt < 2; mt++)
            #pragma unroll
            for (int nt = 0; nt < 4; nt++)
                acc[mt][nt] = (f32x4){0.f, 0.f, 0.f, 0.f};

        const int srow = tid >> 2, sgx = tid & 3;          // threads 0..255
        const __hip_bfloat16* asrc = h0b + (size_t)(r0 + srow) * 832
                                         + (sgx ^ (srow & 3)) * 8;
        const char* bsrc = (const char*)w1sw;

        if (tid < 256)
            __builtin_amdgcn_global_load_lds((const uint32_t*)asrc,
                (uint32_t*)(astg + wave * 1024), 16, 0, 0);
        #pragma unroll
        for (int j2 = 0; j2 < 2; j2++)
            __builtin_amdgcn_global_load_lds(
                (const uint32_t*)(bsrc + j2 * 8192 + tid * 16),
                (uint32_t*)(bstg + j2 * 8192 + wave * 1024), 16, 0, 0);
        __syncthreads();   // vmcnt drain: buf0 ready

        for (int kc = 0; kc < KC1; kc++) {
            const int cur = kc & 1;
            if (kc + 1 < KC1) {
                if (tid < 256)
                    __builtin_amdgcn_global_load_lds(
                        (const uint32_t*)(asrc + (kc + 1) * 32),
                        (uint32_t*)(astg + (cur ^ 1) * 4096 + wave * 1024), 16, 0, 0);
                #pragma unroll
                for (int j2 = 0; j2 < 2; j2++)
                    __builtin_amdgcn_global_load_lds(
                        (const uint32_t*)(bsrc + (size_t)(kc + 1) * PANEL_B + j2 * 8192 + tid * 16),
                        (uint32_t*)(bstg + (cur ^ 1) * 16384 + j2 * 8192 + wave * 1024), 16, 0, 0);
            }
            bf16x8 av[2], bv[4];
            #pragma unroll
            for (int mt = 0; mt < 2; mt++)
                av[mt] = *(const bf16x8*)(astg + cur * 4096
                            + (mh * 32 + mt * 16 + l15) * 64 + swg);
            #pragma unroll
            for (int nt = 0; nt < 4; nt++)
                bv[nt] = *(const bf16x8*)(bstg + cur * 16384
                            + (nq * 64 + nt * 16 + l15) * 64 + swg);
            #pragma unroll
            for (int mt = 0; mt < 2; mt++)
                #pragma unroll
                for (int nt = 0; nt < 4; nt++)
                    acc[mt][nt] = __builtin_amdgcn_mfma_f32_16x16x32_bf16(
                        av[mt], bv[nt], acc[mt][nt], 0, 0, 0);
            __syncthreads();
        }
        #pragma unroll
        for (int nt = 0; nt < 4; nt++) {
            const int n = nq * 64 + nt * 16 + l15;
            const float bias = b1[n];
            #pragma unroll
            for (int mt = 0; mt < 2; mt++) {
                #pragma unroll
                for (int q = 0; q < 4; q++) {
                    const int row = mh * 32 + mt * 16 + g * 4 + q;  // C/D: col=l15, row=g*4+q
                    float v = acc[mt][nt][q] + bias;
                    h1s[row * H1S + n] = __float2bfloat16(fmaxf(v, 0.0f));
                }
            }
        }
    }
    __syncthreads();

    // ---- GEMM2: h2 = relu(h1 @ w2 + b2), M=64 N=128 K=256 ----
    {
        f32x4 acc[2][2];
        #pragma unroll
        for (int mt = 0; mt < 2; mt++)
            #pragma unroll
            for (int nt = 0; nt < 2; nt++)
                acc[mt][nt] = (f32x4){0.f, 0.f, 0.f, 0.f};
        const int nb = nq * 32;
        bf16x8 bb2[3][2];
        #pragma unroll
        for (int p = 0; p < 2; p++)
            #pragma unroll
            for (int nt = 0; nt < 2; nt++)
                bb2[p][nt] = *(const bf16x8*)(w2b + ((p * 128 + nb + nt * 16 + l15) * 32 + g * 8));
        #pragma unroll
        for (int kc = 0; kc < KC2; kc++) {
            const int cur = kc % 3, nxt = (kc + 2) % 3;
            if (kc + 2 < KC2) {
                #pragma unroll
                for (int nt = 0; nt < 2; nt++)
                    bb2[nxt][nt] = *(const bf16x8*)(w2b + (((kc + 2) * 128 + nb + nt * 16 + l15) * 32 + g * 8));
            }
            bf16x8 ab[2];
            #pragma unroll
            for (int mt = 0; mt < 2; mt++)
                ab[mt] = *(const bf16x8*)(h1s + (mh * 32 + mt * 16 + l15) * H1S + kc * 32 + g * 8);
            #pragma unroll
            for (int mt = 0; mt < 2; mt++)
                #pragma unroll
                for (int nt = 0; nt < 2; nt++)
                    acc[mt][nt] = __builtin_amdgcn_mfma_f32_16x16x32_bf16(
                        ab[mt], bb2[cur][nt], acc[mt][nt], 0, 0, 0);
        }
        #pragma unroll
        for (int nt = 0; nt < 2; nt++) {
            const int n = nb + nt * 16 + l15;
            const float bias = b2[n];
            #pragma unroll
            for (int mt = 0; mt < 2; mt++) {
                #pragma unroll
                for (int q = 0; q < 4; q++) {
                    const int row = mh * 32 + mt * 16 + g * 4 + q;
                    float v = acc[mt][nt][q] + bias;
                    h2s[row * H2S + n] = __float2bfloat16(fmaxf(v, 0.0f));  // overlays stage bufs
                }
            }
        }
    }
    __syncthreads();

    // ---- GEMM3: out = h2 @ w3 + b3, M=64 N=16(10) K=128; waves 0..3 ----
    if (wave < 4) {
        f32x4 acc3 = (f32x4){0.f, 0.f, 0.f, 0.f};
        #pragma unroll
        for (int kc = 0; kc < KC3; kc++) {
            bf16x8 a = *(const bf16x8*)(h2s + (wave * 16 + l15) * H2S + kc * 32 + g * 8);
            bf16x8 b = *(const bf16x8*)(w3b + ((kc * 16 + l15) * 32 + g * 8));
            acc3 = __builtin_amdgcn_mfma_f32_16x16x32_bf16(a, b, acc3, 0, 0, 0);
        }
        if (l15 < 10) {
            const float bias = b3[l15];
            #pragma unroll
            for (int q = 0; q < 4; q++) {
                const int row = wave * 16 + g * 4 + q;
                out[(size_t)(r0 + row) * 10 + l15] = acc3[q] + bias;
            }
        }
    }
}

// ---------------------------------------------------------------------------
// Fallback: R3 fused kernel (proven), linear w1lin layout. Safety only.
__global__ __launch_bounds__(256, 2)
void fused_model(const float* __restrict__ x, const float* __restrict__ cw,
                 const __hip_bfloat16* __restrict__ w1b, const float* __restrict__ b1,
                 const __hip_bfloat16* __restrict__ w2b, const float* __restrict__ b2,
                 const __hip_bfloat16* __restrict__ w3b, const float* __restrict__ b3,
                 float* __restrict__ out) {
    __shared__ __align__(16) char smem[MR * H0S * 2 + MR * H1S * 2];
    __hip_bfloat16* h0s = (__hip_bfloat16*)smem;
    __hip_bfloat16* h1s = (__hip_bfloat16*)(smem + MR * H0S * 2);
    __hip_bfloat16* h2s = (__hip_bfloat16*)smem;

    const int tid = threadIdx.x;
    const int r0  = blockIdx.x * MR;

    const float c00 = cw[0], c01 = cw[1], c02 = cw[2];
    const float c10 = cw[3], c11 = cw[4], c12 = cw[5];
    const float c20 = cw[6], c21 = cw[7], c22 = cw[8];

    for (int t = tid; t < MR * 26; t += 256) {
        int r = t / 26;
        int i = t - r * 26;
        const float* xr = x + (size_t)(r0 + r) * 784 + i * 28;
        float4 v[21];
        #pragma unroll
        for (int di = 0; di < 3; di++) {
            const float4* p4 = (const float4*)(xr + di * 28);
            #pragma unroll
            for (int q = 0; q < 7; q++) v[di * 7 + q] = p4[q];
        }
        #pragma unroll
        for (int k = 0; k < 21; k++) PIN4(v[k]);
        float rb[3][28];
        #pragma unroll
        for (int di = 0; di < 3; di++) {
            #pragma unroll
            for (int q = 0; q < 7; q++) {
                rb[di][q*4+0] = v[di*7+q].x; rb[di][q*4+1] = v[di*7+q].y;
                rb[di][q*4+2] = v[di*7+q].z; rb[di][q*4+3] = v[di*7+q].w;
            }
        }
        __hip_bfloat162* hp = (__hip_bfloat162*)(h0s + r * H0S + i * 26);
        #pragma unroll
        for (int k = 0; k < 13; k++) {
            const int j0 = 2 * k, j1 = 2 * k + 1;
            float a0 = c00*rb[0][j0] + c01*rb[0][j0+1] + c02*rb[0][j0+2]
                     + c10*rb[1][j0] + c11*rb[1][j0+1] + c12*rb[1][j0+2]
                     + c20*rb[2][j0] + c21*rb[2][j0+1] + c22*rb[2][j0+2];
            float a1 = c00*rb[0][j1] + c01*rb[0][j1+1] + c02*rb[0][j1+2]
                     + c10*rb[1][j1] + c11*rb[1][j1+1] + c12*rb[1][j1+2]
                     + c20*rb[2][j1] + c21*rb[2][j1+1] + c22*rb[2][j1+2];
            __hip_bfloat162 pr;
            pr.x = __float2bfloat16(a0);
            pr.y = __float2bfloat16(a1);
            hp[k] = pr;
        }
    }
    for (int t = tid; t < MR * 18; t += 256) {
        int r = t / 18;
        int c = t - r * 18;
        ((uint*)(h0s + r * H0S + 676))[c] = 0u;
    }
    __syncthreads();

    const int wave = tid >> 6;
    const int lane = tid & 63;
    const int l15  = lane & 15;
    const int g    = lane >> 4;

    {   // GEMM1 (linear w1lin)
        f32x4 acc[2][4];
        #pragma unroll
        for (int mt = 0; mt < 2; mt++)
            #pragma unroll
            for (int nt = 0; nt < 4; nt++)
                acc[mt][nt] = (f32x4){0.f, 0.f, 0.f, 0.f};
        const int nb = wave * 64;
        bf16x8 ab[3][2], bb[3][4];
        #pragma unroll
        for (int p = 0; p < 2; p++) {
            #pragma unroll
            for (int mt = 0; mt < 2; mt++)
                ab[p][mt] = *(const bf16x8*)(h0s + (mt * 16 + l15) * H0S + p * 32 + g * 8);
            #pragma unroll
            for (int nt = 0; nt < 4; nt++)
                bb[p][nt] = *(const bf16x8*)(w1b + ((p * 256 + nb + nt * 16 + l15) * 32 + g * 8));
        }
        #pragma unroll
        for (int kc = 0; kc < KC1F; kc++) {
            const int cur = kc % 3;
            const int nxt = (kc + 2) % 3;
            if (kc + 2 < KC1F) {
                #pragma unroll
                for (int mt = 0; mt < 2; mt++)
                    ab[nxt][mt] = *(const bf16x8*)(h0s + (mt * 16 + l15) * H0S + (kc + 2) * 32 + g * 8);
                #pragma unroll
                for (int nt = 0; nt < 4; nt++)
                    bb[nxt][nt] = *(const bf16x8*)(w1b + (((kc + 2) * 256 + nb + nt * 16 + l15) * 32 + g * 8));
            }
            #pragma unroll
            for (int mt = 0; mt < 2; mt++)
                #pragma unroll
                for (int nt = 0; nt < 4; nt++)
                    acc[mt][nt] = __builtin_amdgcn_mfma_f32_16x16x32_bf16(
                        ab[cur][mt], bb[cur][nt], acc[mt][nt], 0, 0, 0);
        }
        #pragma unroll
        for (int nt = 0; nt < 4; nt++) {
            const int n = nb + nt * 16 + l15;
            const float bias = b1[n];
            #pragma unroll
            for (int mt = 0; mt < 2; mt++) {
                #pragma unroll
                for (int q = 0; q < 4; q++) {
                    const int row = mt * 16 + g * 4 + q;
                    float v = acc[mt][nt][q] + bias;
                    h1s[row * H1S + n] = __float2bfloat16(fmaxf(v, 0.0f));
                }
            }
        }
    }
    __syncthreads();

    {   // GEMM2
        f32x4 acc[2][2];
        #pragma unroll
        for (int mt = 0; mt < 2; mt++)
            #pragma unroll
            for (int nt = 0; nt < 2; nt++)
                acc[mt][nt] = (f32x4){0.f, 0.f, 0.f, 0.f};
        const int nb = wave * 32;
        bf16x8 ab[3][2], bb[3][2];
        #pragma unroll
        for (int p = 0; p < 2; p++) {
            #pragma unroll
            for (int mt = 0; mt < 2; mt++)
                ab[p][mt] = *(const bf16x8*)(h1s + (mt * 16 + l15) * H1S + p * 32 + g * 8);
            #pragma unroll
            for (int nt = 0; nt < 2; nt++)
                bb[p][nt] = *(const bf16x8*)(w2b + ((p * 128 + nb + nt * 16 + l15) * 32 + g * 8));
        }
        #pragma unroll
        for (int kc = 0; kc < KC2; kc++) {
            const int cur = kc % 3;
            const int nxt = (kc + 2) % 3;
            if (kc + 2 < KC2) {
                #pragma unroll
                for (int mt = 0; mt < 2; mt++)
                    ab[nxt][mt] = *(const bf16x8*)(h1s + (mt * 16 + l15) * H1S + (kc + 2) * 32 + g * 8);
                #pragma unroll
                for (int nt = 0; nt < 2; nt++)
                    bb[nxt][nt] = *(const bf16x8*)(w2b + (((kc + 2) * 128 + nb + nt * 16 + l15) * 32 + g * 8));
            }
            #pragma unroll
            for (int mt = 0; mt < 2; mt++)
                #pragma unroll
                for (int nt = 0; nt < 2; nt++)
                    acc[mt][nt] = __builtin_amdgcn_mfma_f32_16x16x32_bf16(
                        ab[cur][mt], bb[cur][nt], acc[mt][nt], 0, 0, 0);
        }
        #pragma unroll
        for (int nt = 0; nt < 2; nt++) {
            const int n = nb + nt * 16 + l15;
            const float bias = b2[n];
            #pragma unroll
            for (int mt = 0; mt < 2; mt++) {
                #pragma unroll
                for (int q = 0; q < 4; q++) {
                    const int row = mt * 16 + g * 4 + q;
                    float v = acc[mt][nt][q] + bias;
                    h2s[row * H2S + n] = __float2bfloat16(fmaxf(v, 0.0f));
                }
            }
        }
    }
    __syncthreads();

    if (wave < 2) {  // GEMM3
        f32x4 acc3 = (f32x4){0.f, 0.f, 0.f, 0.f};
        #pragma unroll
        for (int kc = 0; kc < KC3; kc++) {
            bf16x8 a = *(const bf16x8*)(h2s + (wave * 16 + l15) * H2S + kc * 32 + g * 8);
            bf16x8 b = *(const bf16x8*)(w3b + ((kc * 16 + l15) * 32 + g * 8));
            acc3 = __builtin_amdgcn_mfma_f32_16x16x32_bf16(a, b, acc3, 0, 0, 0);
        }
        if (l15 < 10) {
            const float bias = b3[l15];
            #pragma unroll
            for (int q = 0; q < 4; q++) {
                const int row = wave * 16 + g * 4 + q;
                out[(size_t)(r0 + row) * 10 + l15] = acc3[q] + bias;
            }
        }
    }
}

extern "C" void kernel_launch(void* const* d_in, const int* in_sizes, int n_in,
                              void* d_out, int out_size, void* d_ws, size_t ws_size,
                              hipStream_t stream) {
    const float* x  = (const float*)d_in[0];
    const float* cw = (const float*)d_in[1];
    const float* w1 = (const float*)d_in[2];
    const float* b1 = (const float*)d_in[3];
    const float* w2 = (const float*)d_in[4];
    const float* b2 = (const float*)d_in[5];
    const float* w3 = (const float*)d_in[6];
    const float* b3 = (const float*)d_in[7];
    float* out = (float*)d_out;

    __hip_bfloat16* w1sw  = (__hip_bfloat16*)d_ws;
    __hip_bfloat16* w1lin = (__hip_bfloat16*)((char*)d_ws + W1SW_BYTES);
    __hip_bfloat16* w2b   = (__hip_bfloat16*)((char*)d_ws + W1SW_BYTES + W1LIN_BYTES);
    __hip_bfloat16* w3b   = w2b + W2B_ELEMS;

    const int pack_total = W1SW_ELEMS + W1LIN_ELEMS + W2B_ELEMS + W3B_ELEMS;  // 428032
    pack_weights<<<(pack_total + 255) / 256, 256, 0, stream>>>(
        w1, w2, w3, w1sw, w1lin, w2b, w3b);

    const size_t need = (size_t)WS_WEIGHTS + H0B_BYTES;   // ~110MB
    if (ws_size >= need) {
        __hip_bfloat16* h0b = (__hip_bfloat16*)((char*)d_ws + WS_WEIGHTS);
        conv_kernel<<<B_ROWS * 26 / 256, 256, 0, stream>>>(x, cw, h0b);
        gemm_kernel<<<B_ROWS / GM, 512, 0, stream>>>(h0b, w1sw, b1, w2b, b2, w3b, b3, out);
    } else {
        fused_model<<<B_ROWS / MR, 256, 0, stream>>>(x, cw, w1lin, b1, w2b, b2, w3b, b3, out);
    }
}